// Round 2
// baseline (19652.472 us; speedup 1.0000x reference)
//
#include <hip/hip_runtime.h>
#include <hip/hip_bf16.h>
#include <hip/hip_fp16.h>
#include <hip/hip_cooperative_groups.h>

namespace cg = cooperative_groups;

typedef _Float16 f16;
typedef _Float16 f16x8 __attribute__((ext_vector_type(8)));
typedef float f32x4 __attribute__((ext_vector_type(4)));

#define B_ 128
#define T_ 512
#define I_ 512
#define H_ 512

// ---------------- workspace layout (bytes) ----------------
static constexpr size_t OFF_LEN   = 0;                       // 128 int
static constexpr size_t OFF_BIAS0 = 1024;                    // 2048 f32
static constexpr size_t OFF_BIAS1 = OFF_BIAS0 + 8192;        // 2048 f32
static constexpr size_t OFF_W0    = 32768;                   // 2048x1024 f16 (reordered h*4+g, [w_ih|w_hh])
static constexpr size_t OFF_W1    = OFF_W0 + 4u*1024u*1024u;
static constexpr size_t OFF_H0A   = OFF_W1 + 4u*1024u*1024u; // 128x512 f16
static constexpr size_t OFF_H0B   = OFF_H0A + 131072;
static constexpr size_t OFF_H1A   = OFF_H0B + 131072;
static constexpr size_t OFF_H1B   = OFF_H1A + 131072;
static constexpr size_t OFF_H1F   = OFF_H1B + 131072;        // 128x512 f32
static constexpr size_t WS_NEED   = OFF_H1F + 262144;

// ---------------- lengths: count rows with sum != 0 ----------------
__global__ __launch_bounds__(512) void k_len(const float* __restrict__ x, int* __restrict__ len) {
    int b = blockIdx.x;
    const float4* row = (const float4*)(x + ((size_t)b * T_ + threadIdx.x) * I_);
    float s = 0.f;
    #pragma unroll 4
    for (int i = 0; i < I_ / 4; ++i) { float4 v = row[i]; s += v.x + v.y + v.z + v.w; }
    int cnt = __syncthreads_count(s != 0.0f);
    if (threadIdx.x == 0) len[b] = cnt;
}

// ---------------- weight convert: reorder rows to h*4+gate, concat [w_ih|w_hh], f32->f16 ----------------
__global__ __launch_bounds__(256) void k_wcvt(const float* __restrict__ wih, const float* __restrict__ whh,
                                              const float* __restrict__ bih, const float* __restrict__ bhh,
                                              f16* __restrict__ W, float* __restrict__ bias) {
    int r = blockIdx.x;          // reordered row 0..2047
    int h = r >> 2, g = r & 3;
    int src = g * 512 + h;
    const float* a = wih + (size_t)src * 512;
    const float* bsrc = whh + (size_t)src * 512;
    f16* dst = W + (size_t)r * 1024;
    #pragma unroll
    for (int j = 0; j < 2; ++j) {
        int k = threadIdx.x + j * 256;
        dst[k]       = (f16)a[k];
        dst[k + 512] = (f16)bsrc[k];
    }
    if (threadIdx.x == 0) bias[r] = bih[src] + bhh[src];
}

// ---------------- persistent cooperative kernel ----------------
// 256 blocks x 512 threads, 1 block/CU (LDS-bounded).
// Block = (layer: bid>>7) x (batch-group: (bid>>5)&3, 32 rows) x (col-group: bid&31, 64 gate rows).
// Weights (64 x 1024 f16 = 128 KB) pinned in LDS, XOR-swizzled. A streamed global->regs.
// c-state + h-carry in registers. One grid.sync() per pipelined timestep.
__global__ __launch_bounds__(512, 2) void k_persist(
    const float* __restrict__ x,
    const f16* __restrict__ W0, const f16* __restrict__ W1,
    const float* __restrict__ bias0, const float* __restrict__ bias1,
    const int* __restrict__ len,
    f16* __restrict__ h0a, f16* __restrict__ h0b,
    f16* __restrict__ h1a, f16* __restrict__ h1b,
    float* __restrict__ h1f)
{
    extern __shared__ char lds[];
    char* Wlds = lds;                         // 131072 B
    char* Gs   = lds + 131072;                // 8192 B gate scratch [32][64] f32, swizzled

    cg::grid_group grid = cg::this_grid();

    const int tid = threadIdx.x;
    const int bid = blockIdx.x;
    const int layer = bid >> 7;
    const int bg    = (bid >> 5) & 3;
    const int cgp   = bid & 31;
    const int bbase = bg * 32;
    const int nbase = cgp * 64;               // reordered gate-row base
    const int ubase = nbase >> 2;             // h-unit base

    const int wid = tid >> 6, lane = tid & 63;
    const int msub = wid >> 2, nsub = wid & 3;

    // ---- stage weights into LDS (one-off, swizzled) ----
    {
        const f16* Wsrc = (layer ? W1 : W0) + (size_t)nbase * 1024;
        int r = tid >> 3, e = tid & 7;
        const f16* src = Wsrc + (size_t)r * 1024 + e * 128;
        char* row = Wlds + r * 2048;
        int sw = (r & 7) << 4;
        #pragma unroll
        for (int j = 0; j < 16; ++j) {
            int byte = e * 256 + j * 16;
            *(f16x8*)(row + (byte ^ sw)) = *(const f16x8*)(src + j * 8);
        }
    }

    // ---- per-thread epilogue state: (batch eb, h-unit eu) ----
    const int eb = tid >> 4;                  // 0..31
    const int eu = tid & 15;                  // 0..15
    const int lb = len[bbase + eb];
    const float4 bias4 = *(const float4*)((layer ? bias1 : bias0) + nbase + eu * 4);
    float c_reg = 0.f;
    f16   h_reg = (f16)0.f;

    // ---- wave-level MFMA constants ----
    const int brow   = bbase + msub * 16 + (lane & 15);   // batch row for A frag
    const int nrow_l = nsub * 16 + (lane & 15);           // local gate row for B frag
    const char* Brow = Wlds + nrow_l * 2048;
    const int bsw    = (nrow_l & 7) << 4;
    const int koff8  = (lane >> 4) << 3;                  // 0,8,16,24

    __syncthreads();

    for (int t = 0; t <= T_; ++t) {
        const int step = layer ? (t - 1) : t;
        const bool active = (step >= 0) && (step < T_);
        f32x4 acc = {};

        if (active) {
            if (layer == 0) {
                // K [0,512): x[:,t,:] f32 ; K [512,1024): h0(t-1)
                const f16* hprev = ((t & 1) == 0) ? h0b : h0a;        // h0(t-1)
                const float* xp = x + ((size_t)brow * T_ + t) * I_ + koff8;
                const f16* hp  = hprev + (size_t)brow * 512 + koff8;
                #pragma unroll
                for (int ks = 0; ks < 16; ++ks) {
                    const float4* q = (const float4*)(xp + ks * 32);
                    float4 v0 = q[0], v1 = q[1];
                    f16x8 a = { (f16)v0.x, (f16)v0.y, (f16)v0.z, (f16)v0.w,
                                (f16)v1.x, (f16)v1.y, (f16)v1.z, (f16)v1.w };
                    f16x8 b = *(const f16x8*)(Brow + ((ks * 64 + koff8 * 2) ^ bsw));
                    acc = __builtin_amdgcn_mfma_f32_16x16x32_f16(a, b, acc, 0, 0, 0);
                }
                #pragma unroll
                for (int ks = 0; ks < 16; ++ks) {
                    f16x8 a = *(const f16x8*)(hp + ks * 32);
                    f16x8 b = *(const f16x8*)(Brow + (((ks + 16) * 64 + koff8 * 2) ^ bsw));
                    acc = __builtin_amdgcn_mfma_f32_16x16x32_f16(a, b, acc, 0, 0, 0);
                }
            } else {
                // K [0,512): h0(s) ; K [512,1024): h1(s-1)
                const int s = step;
                const f16* inA = ((s & 1) == 0) ? h0a : h0b;          // h0(s)
                const f16* inB = ((s & 1) == 0) ? h1b : h1a;          // h1(s-1)
                const f16* ap = inA + (size_t)brow * 512 + koff8;
                const f16* bp = inB + (size_t)brow * 512 + koff8;
                #pragma unroll
                for (int ks = 0; ks < 16; ++ks) {
                    f16x8 a = *(const f16x8*)(ap + ks * 32);
                    f16x8 b = *(const f16x8*)(Brow + ((ks * 64 + koff8 * 2) ^ bsw));
                    acc = __builtin_amdgcn_mfma_f32_16x16x32_f16(a, b, acc, 0, 0, 0);
                }
                #pragma unroll
                for (int ks = 0; ks < 16; ++ks) {
                    f16x8 a = *(const f16x8*)(bp + ks * 32);
                    f16x8 b = *(const f16x8*)(Brow + (((ks + 16) * 64 + koff8 * 2) ^ bsw));
                    acc = __builtin_amdgcn_mfma_f32_16x16x32_f16(a, b, acc, 0, 0, 0);
                }
            }
            // scatter acc -> gate LDS (swizzled [32][64] f32)
            {
                int n  = nsub * 16 + (lane & 15);
                int mb = msub * 16 + ((lane >> 4) << 2);
                #pragma unroll
                for (int r = 0; r < 4; ++r) {
                    int m = mb + r;
                    *(float*)(Gs + ((m * 256 + n * 4) ^ ((m & 7) << 4))) = acc[r];
                }
            }
        }
        __syncthreads();
        if (active) {
            f32x4 gv = *(f32x4*)(Gs + ((eb * 256 + eu * 16) ^ ((eb & 7) << 4)));
            float gi = gv[0] + bias4.x, gf = gv[1] + bias4.y;
            float gg = gv[2] + bias4.z, go = gv[3] + bias4.w;
            float si = 1.f / (1.f + expf(-gi));
            float sf = 1.f / (1.f + expf(-gf));
            float sg = tanhf(gg);
            float so = 1.f / (1.f + expf(-go));
            float cn = sf * c_reg + si * sg;
            float hn = so * tanhf(cn);
            bool msk = step < lb;
            if (msk) { c_reg = cn; h_reg = (f16)hn; }
            size_t idx = (size_t)(bbase + eb) * 512 + ubase + eu;
            f16* h_w;
            if (layer == 0) h_w = ((t & 1) == 0) ? h0a : h0b;          // h0(t) slot t&1
            else            h_w = ((step & 1) == 0) ? h1a : h1b;       // h1(s) slot s&1
            h_w[idx] = h_reg;
            if (layer == 1 && msk) h1f[idx] = hn;
        }
        grid.sync();
    }
}

// ---------------- final FC: out[b][o] = h1 . w_fc[o] + b_fc[o] ----------------
__global__ __launch_bounds__(256) void k_fc(const float* __restrict__ h1f,
                                            const float* __restrict__ wfc,
                                            const float* __restrict__ bfc,
                                            float* __restrict__ out) {
    int b = blockIdx.x;
    float s0 = 0, s1 = 0, s2 = 0, s3 = 0;
    for (int h = threadIdx.x; h < 512; h += 256) {
        float v = h1f[(size_t)b * 512 + h];
        s0 += v * wfc[h];
        s1 += v * wfc[512 + h];
        s2 += v * wfc[1024 + h];
        s3 += v * wfc[1536 + h];
    }
    #pragma unroll
    for (int off = 32; off; off >>= 1) {
        s0 += __shfl_down(s0, off);
        s1 += __shfl_down(s1, off);
        s2 += __shfl_down(s2, off);
        s3 += __shfl_down(s3, off);
    }
    __shared__ float red[4][4];
    int wid = threadIdx.x >> 6;
    if ((threadIdx.x & 63) == 0) { red[wid][0] = s0; red[wid][1] = s1; red[wid][2] = s2; red[wid][3] = s3; }
    __syncthreads();
    if (threadIdx.x < 4) {
        float s = red[0][threadIdx.x] + red[1][threadIdx.x] + red[2][threadIdx.x] + red[3][threadIdx.x]
                + bfc[threadIdx.x];
        out[b * 4 + threadIdx.x] = s;
    }
}

extern "C" void kernel_launch(void* const* d_in, const int* in_sizes, int n_in,
                              void* d_out, int out_size, void* d_ws, size_t ws_size,
                              hipStream_t stream) {
    const float* x    = (const float*)d_in[0];
    const float* wih0 = (const float*)d_in[1];
    const float* whh0 = (const float*)d_in[2];
    const float* bih0 = (const float*)d_in[3];
    const float* bhh0 = (const float*)d_in[4];
    const float* wih1 = (const float*)d_in[5];
    const float* whh1 = (const float*)d_in[6];
    const float* bih1 = (const float*)d_in[7];
    const float* bhh1 = (const float*)d_in[8];
    const float* wfc  = (const float*)d_in[9];
    const float* bfc  = (const float*)d_in[10];

    if (ws_size < WS_NEED) return;

    char* ws = (char*)d_ws;
    int*   len   = (int*)(ws + OFF_LEN);
    float* bias0 = (float*)(ws + OFF_BIAS0);
    float* bias1 = (float*)(ws + OFF_BIAS1);
    f16*   W0    = (f16*)(ws + OFF_W0);
    f16*   W1    = (f16*)(ws + OFF_W1);
    f16*   h0a   = (f16*)(ws + OFF_H0A);
    f16*   h0b   = (f16*)(ws + OFF_H0B);
    f16*   h1a   = (f16*)(ws + OFF_H1A);
    f16*   h1b   = (f16*)(ws + OFF_H1B);
    float* h1f   = (float*)(ws + OFF_H1F);

    // zero recurrent state (h buffers + h1f)
    hipMemsetAsync(ws + OFF_H0A, 0, WS_NEED - OFF_H0A, stream);

    k_len<<<B_, 512, 0, stream>>>(x, len);
    k_wcvt<<<2048, 256, 0, stream>>>(wih0, whh0, bih0, bhh0, W0, bias0);
    k_wcvt<<<2048, 256, 0, stream>>>(wih1, whh1, bih1, bhh1, W1, bias1);

    const unsigned ldsBytes = 131072u + 8192u;
    hipFuncSetAttribute((const void*)k_persist, hipFuncAttributeMaxDynamicSharedMemorySize,
                        (int)ldsBytes);
    void* kargs[] = {
        (void*)&x, (void*)&W0, (void*)&W1, (void*)&bias0, (void*)&bias1, (void*)&len,
        (void*)&h0a, (void*)&h0b, (void*)&h1a, (void*)&h1b, (void*)&h1f
    };
    hipLaunchCooperativeKernel((const void*)k_persist, dim3(256), dim3(512),
                               kargs, ldsBytes, stream);

    k_fc<<<B_, 256, 0, stream>>>(h1f, wfc, bfc, (float*)d_out);
}

// Round 3
// 14129.111 us; speedup vs baseline: 1.3909x; 1.3909x over previous
//
#include <hip/hip_runtime.h>
#include <hip/hip_fp16.h>

typedef _Float16 f16;
typedef _Float16 f16x8 __attribute__((ext_vector_type(8)));
typedef _Float16 f16x4 __attribute__((ext_vector_type(4)));
typedef float f32x4 __attribute__((ext_vector_type(4)));

#define B_ 128
#define T_ 512
#define I_ 512
#define H_ 512
#define NBLK 128   // persistent blocks = barrier participants

// ---------------- workspace layout (bytes) ----------------
static constexpr size_t OFF_BAR   = 0;                         // 2 ints (cnt, gen)
static constexpr size_t OFF_LEN   = 64;                        // 128 int
static constexpr size_t OFF_BIAS0 = 1024;                      // 2048 f32
static constexpr size_t OFF_BIAS1 = 9216;                      // 2048 f32
static constexpr size_t OFF_W0    = 32768;                     // 2048x1024 f16, rows u*4+g, [w_ih|w_hh]
static constexpr size_t OFF_W1    = OFF_W0 + 4u*1024u*1024u;
static constexpr size_t OFF_H0A   = OFF_W1 + 4u*1024u*1024u;   // 128x512 f16 each
static constexpr size_t OFF_H0B   = OFF_H0A + 131072;
static constexpr size_t OFF_H1A   = OFF_H0B + 131072;
static constexpr size_t OFF_H1B   = OFF_H1A + 131072;
static constexpr size_t OFF_H1F   = OFF_H1B + 131072;          // 128x512 f32
static constexpr size_t WS_BASE   = OFF_H1F + 262144;          // ~9.2 MB
static constexpr size_t OFF_X0    = WS_BASE;                   // f16 [T][B][2048] (x@Wih0^T + b0)
static constexpr size_t X0_SZ     = (size_t)T_ * 128 * 2048 * 2;
static constexpr size_t WS_PRE    = OFF_X0 + X0_SZ;            // ~265 MB

// ---------------- hand-rolled grid barrier ----------------
// Monotonic arrival counter + generation flag in L3 (agent-scope atomics).
// Release fence: wbL2 (cheap: only h slices dirty). Acquire fence: inv L1/L2.
__device__ __forceinline__ void gridbar(int* bar, int nb, int it) {
    __syncthreads();                     // drains each wave's vmcnt (stores in L2)
    if (threadIdx.x == 0) {
        __builtin_amdgcn_fence(__ATOMIC_RELEASE, "agent");   // flush dirty L2 -> L3
        int a = __hip_atomic_fetch_add(&bar[0], 1, __ATOMIC_RELAXED, __HIP_MEMORY_SCOPE_AGENT);
        if (a == nb * (it + 1) - 1) {
            __hip_atomic_store(&bar[1], it + 1, __ATOMIC_RELAXED, __HIP_MEMORY_SCOPE_AGENT);
        } else {
            while (__hip_atomic_load(&bar[1], __ATOMIC_RELAXED, __HIP_MEMORY_SCOPE_AGENT) < it + 1)
                __builtin_amdgcn_s_sleep(1);
        }
        __builtin_amdgcn_fence(__ATOMIC_ACQUIRE, "agent");   // invalidate L1/L2
    }
    __syncthreads();
}

// ---------------- lengths: count rows with sum != 0 ----------------
__global__ __launch_bounds__(512) void k_len(const float* __restrict__ x, int* __restrict__ len) {
    int b = blockIdx.x;
    const float4* row = (const float4*)(x + ((size_t)b * T_ + threadIdx.x) * I_);
    float s = 0.f;
    #pragma unroll 4
    for (int i = 0; i < I_ / 4; ++i) { float4 v = row[i]; s += v.x + v.y + v.z + v.w; }
    int cnt = __syncthreads_count(s != 0.0f);
    if (threadIdx.x == 0) len[b] = cnt;
}

// ---------------- weight convert: rows u*4+gate, concat [w_ih|w_hh], f32->f16 ----------------
__global__ __launch_bounds__(256) void k_wcvt(const float* __restrict__ wih, const float* __restrict__ whh,
                                              const float* __restrict__ bih, const float* __restrict__ bhh,
                                              f16* __restrict__ W, float* __restrict__ bias) {
    int r = blockIdx.x;          // reordered row 0..2047 = u*4+g
    int h = r >> 2, g = r & 3;
    int src = g * 512 + h;
    const float* a = wih + (size_t)src * 512;
    const float* bsrc = whh + (size_t)src * 512;
    f16* dst = W + (size_t)r * 1024;
    #pragma unroll
    for (int j = 0; j < 2; ++j) {
        int k = threadIdx.x + j * 256;
        dst[k]       = (f16)a[k];
        dst[k + 512] = (f16)bsrc[k];
    }
    if (threadIdx.x == 0) bias[r] = bih[src] + bhh[src];
}

// ---------------- X0 precompute: X0[t][b][:] = x[b][t][:] @ w_ih0^T + b0 (reordered cols) ----------------
// grid (cg=32, b=128, tc=4), 256 threads. A = W rows (LDS, swizzled), B = x (global f32 -> f16).
__global__ __launch_bounds__(256) void k_xgemm(const float* __restrict__ x, const f16* __restrict__ W0,
                                               const float* __restrict__ bias0, f16* __restrict__ X0) {
    __shared__ char lds[65536];
    const int cg = blockIdx.x, b = blockIdx.y, tc = blockIdx.z;
    const int tid = threadIdx.x;
    const int wv = tid >> 6, lane = tid & 63;
    const int l16 = lane & 15, l4 = lane >> 4;
    const int nf = wv;
    {   // stage ih-half of this col-group's 64 weight rows: 64 x 512 f16, swizzled
        const int r = tid >> 2, e = tid & 3;
        const f16* src = W0 + (size_t)(cg * 64 + r) * 1024 + e * 128;
        char* rowp = lds + r * 1024;
        const int sw = (r & 7) << 4;
        #pragma unroll
        for (int j = 0; j < 16; ++j) {
            const int byte = e * 256 + j * 16;
            *(f16x8*)(rowp + (byte ^ sw)) = *(const f16x8*)(src + j * 8);
        }
    }
    __syncthreads();
    const int row_l = nf * 16 + l16;
    const char* Wrow = lds + row_l * 1024;
    const int wsw = (row_l & 7) << 4;
    const int koff = l4 * 8;
    f32x4 acc[8] = {};
    #pragma unroll 4
    for (int ks = 0; ks < 16; ++ks) {
        f16x8 aw = *(const f16x8*)(Wrow + (((ks * 32 + koff) * 2) ^ wsw));
        #pragma unroll
        for (int mf = 0; mf < 8; ++mf) {
            const int tt = tc * 128 + mf * 16 + l16;
            const float* xp = x + ((size_t)b * 512 + tt) * 512 + ks * 32 + koff;
            const float4 p0 = *(const float4*)xp;
            const float4 p1 = *(const float4*)(xp + 4);
            f16x8 v = { (f16)p0.x,(f16)p0.y,(f16)p0.z,(f16)p0.w,
                        (f16)p1.x,(f16)p1.y,(f16)p1.z,(f16)p1.w };
            acc[mf] = __builtin_amdgcn_mfma_f32_16x16x32_f16(aw, v, acc[mf], 0, 0, 0);
        }
    }
    const float4 b4 = *(const float4*)(bias0 + cg * 64 + nf * 16 + l4 * 4);
    const float bb[4] = { b4.x, b4.y, b4.z, b4.w };
    #pragma unroll
    for (int mf = 0; mf < 8; ++mf) {
        const int tt = tc * 128 + mf * 16 + l16;
        f16x4 v;
        #pragma unroll
        for (int g = 0; g < 4; ++g) v[g] = (f16)(acc[mf][g] + bb[g]);
        *(f16x4*)(X0 + ((size_t)tt * 128 + b) * 2048 + cg * 64 + nf * 16 + l4 * 4) = v;
    }
}

// ---------------- persistent kernel: 128 blocks x 512 thr, hand barrier per step ----------------
// Block = layer (bid>>6) x batch-half (bid>>5)&1 x col-group (bid&31: 64 gate rows = 16 units).
// Swapped MFMA: A = W rows (LDS), B = activations (global). Lane owns all 4 gates of one unit
// -> epilogue fully in-register (c-state, h-carry in regs), no in-loop __syncthreads.
__global__ __launch_bounds__(512) void k_persist(
    const float* __restrict__ x,
    const f16* __restrict__ W0, const f16* __restrict__ W1,
    const float* __restrict__ bias0, const float* __restrict__ bias1,
    const int* __restrict__ len,
    f16* __restrict__ h0a, f16* __restrict__ h0b,
    f16* __restrict__ h1a, f16* __restrict__ h1b,
    float* __restrict__ h1f,
    const f16* __restrict__ X0, int pre, int* bar)
{
    extern __shared__ char lds[];   // 131072: this block's 64 weight rows, K=1024, swizzled
    const int tid = threadIdx.x;
    const int bid = blockIdx.x;
    const int layer = bid >> 6;
    const int bg = (bid >> 5) & 1;
    const int cg = bid & 31;
    const int wv = tid >> 6, lane = tid & 63;
    const int nf = wv & 3, mh = wv >> 2;
    const int l16 = lane & 15, l4 = lane >> 4;

    {   // one-off weight staging
        const f16* Wsrc = (layer ? W1 : W0) + (size_t)(cg * 64) * 1024;
        const int r = tid >> 3, e = tid & 7;
        const f16* src = Wsrc + (size_t)r * 1024 + e * 128;
        char* rowp = lds + r * 2048;
        const int sw = (r & 7) << 4;
        #pragma unroll
        for (int j = 0; j < 16; ++j) {
            const int byte = e * 256 + j * 16;
            *(f16x8*)(rowp + (byte ^ sw)) = *(const f16x8*)(src + j * 8);
        }
    }

    const int row_l = nf * 16 + l16;             // A-frag weight row (lane&15 based)
    const char* Wrow = lds + row_l * 2048;
    const int wsw = (row_l & 7) << 4;
    const int koff = l4 * 8;                     // k sub-offset within K=32
    const int u = cg * 16 + nf * 4 + l4;         // this lane's h-unit (D-row based)
    const int b0 = bg * 64 + mh * 32 + l16;      // D-col batches (two m-frags)
    const int b1 = b0 + 16;
    const int lb0 = len[b0], lb1 = len[b1];
    float4 bias4 = make_float4(0.f, 0.f, 0.f, 0.f);
    if (layer) bias4 = *(const float4*)(bias1 + u * 4);
    else if (!pre) bias4 = *(const float4*)(bias0 + u * 4);
    float c0r = 0.f, c1r = 0.f;
    f16 hc0 = (f16)0.f, hc1 = (f16)0.f;

    __syncthreads();

    for (int t = 0; t <= T_; ++t) {
        const int step = layer ? (t - 1) : t;
        const bool active = (step >= 0) && (step < T_);
        if (active) {
            f32x4 acc0 = {}, acc1 = {};
            float xg0[4], xg1[4];
            if (layer == 0 && pre) {   // gate base = precomputed x-part (incl. bias0)
                const f16x4 xa = *(const f16x4*)(X0 + ((size_t)t * 128 + b0) * 2048 + u * 4);
                const f16x4 xb = *(const f16x4*)(X0 + ((size_t)t * 128 + b1) * 2048 + u * 4);
                #pragma unroll
                for (int g = 0; g < 4; ++g) { xg0[g] = (float)xa[g]; xg1[g] = (float)xb[g]; }
            } else {
                xg0[0] = xg1[0] = bias4.x; xg0[1] = xg1[1] = bias4.y;
                xg0[2] = xg1[2] = bias4.z; xg0[3] = xg1[3] = bias4.w;
            }

            if (layer == 0) {
                const f16* hprev = (t & 1) ? h0a : h0b;            // h0(t-1)
                const f16* hp0 = hprev + (size_t)b0 * 512 + koff;
                const f16* hp1 = hprev + (size_t)b1 * 512 + koff;
                if (!pre) {                                        // x-part in-loop fallback
                    const float* xp0 = x + ((size_t)b0 * 512 + t) * 512 + koff;
                    const float* xp1 = x + ((size_t)b1 * 512 + t) * 512 + koff;
                    #pragma unroll
                    for (int ks = 0; ks < 16; ++ks) {
                        f16x8 aw = *(const f16x8*)(Wrow + (((ks * 32 + koff) * 2) ^ wsw));
                        const float4 p0 = *(const float4*)(xp0 + ks * 32);
                        const float4 p1 = *(const float4*)(xp0 + ks * 32 + 4);
                        const float4 p2 = *(const float4*)(xp1 + ks * 32);
                        const float4 p3 = *(const float4*)(xp1 + ks * 32 + 4);
                        f16x8 v0 = { (f16)p0.x,(f16)p0.y,(f16)p0.z,(f16)p0.w,
                                     (f16)p1.x,(f16)p1.y,(f16)p1.z,(f16)p1.w };
                        f16x8 v1 = { (f16)p2.x,(f16)p2.y,(f16)p2.z,(f16)p2.w,
                                     (f16)p3.x,(f16)p3.y,(f16)p3.z,(f16)p3.w };
                        acc0 = __builtin_amdgcn_mfma_f32_16x16x32_f16(aw, v0, acc0, 0, 0, 0);
                        acc1 = __builtin_amdgcn_mfma_f32_16x16x32_f16(aw, v1, acc1, 0, 0, 0);
                    }
                }
                #pragma unroll
                for (int ks = 0; ks < 16; ++ks) {                  // h-part (w_hh at K offset 512)
                    f16x8 aw = *(const f16x8*)(Wrow + ((1024 + (ks * 32 + koff) * 2) ^ wsw));
                    f16x8 v0 = *(const f16x8*)(hp0 + ks * 32);
                    f16x8 v1 = *(const f16x8*)(hp1 + ks * 32);
                    acc0 = __builtin_amdgcn_mfma_f32_16x16x32_f16(aw, v0, acc0, 0, 0, 0);
                    acc1 = __builtin_amdgcn_mfma_f32_16x16x32_f16(aw, v1, acc1, 0, 0, 0);
                }
            } else {
                const int s = step;
                const f16* hin = (s & 1) ? h0b : h0a;              // h0(s)
                const f16* hpr = (s & 1) ? h1a : h1b;              // h1(s-1)
                const f16* ip0 = hin + (size_t)b0 * 512 + koff;
                const f16* ip1 = hin + (size_t)b1 * 512 + koff;
                const f16* rp0 = hpr + (size_t)b0 * 512 + koff;
                const f16* rp1 = hpr + (size_t)b1 * 512 + koff;
                #pragma unroll
                for (int ks = 0; ks < 16; ++ks) {                  // ih-part on h0(s)
                    f16x8 aw = *(const f16x8*)(Wrow + (((ks * 32 + koff) * 2) ^ wsw));
                    f16x8 v0 = *(const f16x8*)(ip0 + ks * 32);
                    f16x8 v1 = *(const f16x8*)(ip1 + ks * 32);
                    acc0 = __builtin_amdgcn_mfma_f32_16x16x32_f16(aw, v0, acc0, 0, 0, 0);
                    acc1 = __builtin_amdgcn_mfma_f32_16x16x32_f16(aw, v1, acc1, 0, 0, 0);
                }
                #pragma unroll
                for (int ks = 0; ks < 16; ++ks) {                  // hh-part on h1(s-1)
                    f16x8 aw = *(const f16x8*)(Wrow + ((1024 + (ks * 32 + koff) * 2) ^ wsw));
                    f16x8 v0 = *(const f16x8*)(rp0 + ks * 32);
                    f16x8 v1 = *(const f16x8*)(rp1 + ks * 32);
                    acc0 = __builtin_amdgcn_mfma_f32_16x16x32_f16(aw, v0, acc0, 0, 0, 0);
                    acc1 = __builtin_amdgcn_mfma_f32_16x16x32_f16(aw, v1, acc1, 0, 0, 0);
                }
            }

            // in-register epilogue: lane has gates (i,f,g,o) for unit u, batches b0,b1
            float gi0 = acc0[0] + xg0[0], gf0 = acc0[1] + xg0[1];
            float gg0 = acc0[2] + xg0[2], go0 = acc0[3] + xg0[3];
            float gi1 = acc1[0] + xg1[0], gf1 = acc1[1] + xg1[1];
            float gg1 = acc1[2] + xg1[2], go1 = acc1[3] + xg1[3];
            float cn0 = (1.f / (1.f + expf(-gf0))) * c0r + (1.f / (1.f + expf(-gi0))) * tanhf(gg0);
            float hn0 = (1.f / (1.f + expf(-go0))) * tanhf(cn0);
            float cn1 = (1.f / (1.f + expf(-gf1))) * c1r + (1.f / (1.f + expf(-gi1))) * tanhf(gg1);
            float hn1 = (1.f / (1.f + expf(-go1))) * tanhf(cn1);
            if (step < lb0) { c0r = cn0; hc0 = (f16)hn0; }
            if (step < lb1) { c1r = cn1; hc1 = (f16)hn1; }
            f16* hw;
            if (layer == 0) hw = (t & 1) ? h0b : h0a;              // h0(t)
            else            hw = (step & 1) ? h1b : h1a;           // h1(s)
            hw[(size_t)b0 * 512 + u] = hc0;
            hw[(size_t)b1 * 512 + u] = hc1;
            if (layer) {
                if (step < lb0) h1f[(size_t)b0 * 512 + u] = hn0;
                if (step < lb1) h1f[(size_t)b1 * 512 + u] = hn1;
            }
        }
        gridbar(bar, NBLK, t);
    }
}

// ---------------- final FC ----------------
__global__ __launch_bounds__(256) void k_fc(const float* __restrict__ h1f,
                                            const float* __restrict__ wfc,
                                            const float* __restrict__ bfc,
                                            float* __restrict__ out) {
    int b = blockIdx.x;
    float s0 = 0, s1 = 0, s2 = 0, s3 = 0;
    for (int h = threadIdx.x; h < 512; h += 256) {
        float v = h1f[(size_t)b * 512 + h];
        s0 += v * wfc[h];
        s1 += v * wfc[512 + h];
        s2 += v * wfc[1024 + h];
        s3 += v * wfc[1536 + h];
    }
    #pragma unroll
    for (int off = 32; off; off >>= 1) {
        s0 += __shfl_down(s0, off);
        s1 += __shfl_down(s1, off);
        s2 += __shfl_down(s2, off);
        s3 += __shfl_down(s3, off);
    }
    __shared__ float red[4][4];
    int wid = threadIdx.x >> 6;
    if ((threadIdx.x & 63) == 0) { red[wid][0] = s0; red[wid][1] = s1; red[wid][2] = s2; red[wid][3] = s3; }
    __syncthreads();
    if (threadIdx.x < 4) {
        float s = red[0][threadIdx.x] + red[1][threadIdx.x] + red[2][threadIdx.x] + red[3][threadIdx.x]
                + bfc[threadIdx.x];
        out[b * 4 + threadIdx.x] = s;
    }
}

extern "C" void kernel_launch(void* const* d_in, const int* in_sizes, int n_in,
                              void* d_out, int out_size, void* d_ws, size_t ws_size,
                              hipStream_t stream) {
    const float* x    = (const float*)d_in[0];
    const float* wih0 = (const float*)d_in[1];
    const float* whh0 = (const float*)d_in[2];
    const float* bih0 = (const float*)d_in[3];
    const float* bhh0 = (const float*)d_in[4];
    const float* wih1 = (const float*)d_in[5];
    const float* whh1 = (const float*)d_in[6];
    const float* bih1 = (const float*)d_in[7];
    const float* bhh1 = (const float*)d_in[8];
    const float* wfc  = (const float*)d_in[9];
    const float* bfc  = (const float*)d_in[10];

    if (ws_size < WS_BASE) return;
    const int pre = (ws_size >= WS_PRE) ? 1 : 0;

    char* ws = (char*)d_ws;
    int*   bar   = (int*)(ws + OFF_BAR);
    int*   len   = (int*)(ws + OFF_LEN);
    float* bias0 = (float*)(ws + OFF_BIAS0);
    float* bias1 = (float*)(ws + OFF_BIAS1);
    f16*   W0    = (f16*)(ws + OFF_W0);
    f16*   W1    = (f16*)(ws + OFF_W1);
    f16*   h0a   = (f16*)(ws + OFF_H0A);
    f16*   h0b   = (f16*)(ws + OFF_H0B);
    f16*   h1a   = (f16*)(ws + OFF_H1A);
    f16*   h1b   = (f16*)(ws + OFF_H1B);
    float* h1f   = (float*)(ws + OFF_H1F);
    f16*   X0p   = (f16*)(ws + OFF_X0);

    hipMemsetAsync(ws + OFF_BAR, 0, 64, stream);
    hipMemsetAsync(ws + OFF_H0A, 0, WS_BASE - OFF_H0A, stream);

    k_len<<<B_, 512, 0, stream>>>(x, len);
    k_wcvt<<<2048, 256, 0, stream>>>(wih0, whh0, bih0, bhh0, W0, bias0);
    k_wcvt<<<2048, 256, 0, stream>>>(wih1, whh1, bih1, bhh1, W1, bias1);
    if (pre) k_xgemm<<<dim3(32, 128, 4), 256, 0, stream>>>(x, W0, bias0, X0p);

    hipFuncSetAttribute((const void*)k_persist, hipFuncAttributeMaxDynamicSharedMemorySize, 131072);
    const f16* X0c = X0p;
    void* kargs[] = {
        (void*)&x, (void*)&W0, (void*)&W1, (void*)&bias0, (void*)&bias1, (void*)&len,
        (void*)&h0a, (void*)&h0b, (void*)&h1a, (void*)&h1b, (void*)&h1f,
        (void*)&X0c, (void*)&pre, (void*)&bar
    };
    hipLaunchCooperativeKernel((const void*)k_persist, dim3(NBLK), dim3(512),
                               kargs, 131072, stream);

    k_fc<<<B_, 256, 0, stream>>>(h1f, wfc, bfc, (float*)d_out);
}

// Round 4
// 12096.552 us; speedup vs baseline: 1.6246x; 1.1680x over previous
//
#include <hip/hip_runtime.h>
#include <hip/hip_fp16.h>

typedef _Float16 f16;
typedef _Float16 f16x8 __attribute__((ext_vector_type(8)));
typedef _Float16 f16x4 __attribute__((ext_vector_type(4)));
typedef float f32x4 __attribute__((ext_vector_type(4)));

#define B_ 128
#define T_ 512
#define I_ 512
#define H_ 512
#define NBLK 128

// ---------------- workspace layout (bytes) ----------------
static constexpr size_t OFF_BAR   = 0;                         // 2 groups x (cnt,flag), 128B apart
static constexpr size_t OFF_LEN   = 512;                       // 128 int
static constexpr size_t OFF_BIAS0 = 1024;                      // 2048 f32
static constexpr size_t OFF_BIAS1 = 9216;                      // 2048 f32
static constexpr size_t OFF_W0    = 32768;                     // 2048x1024 f16, rows u*4+g, [w_ih|w_hh]
static constexpr size_t OFF_W1    = OFF_W0 + 4u*1024u*1024u;
static constexpr size_t OFF_H0A   = OFF_W1 + 4u*1024u*1024u;   // 128x512 f16 each
static constexpr size_t OFF_H0B   = OFF_H0A + 131072;
static constexpr size_t OFF_H1A   = OFF_H0B + 131072;
static constexpr size_t OFF_H1B   = OFF_H1A + 131072;
static constexpr size_t OFF_H1F   = OFF_H1B + 131072;          // 128x512 f32
static constexpr size_t WS_BASE   = OFF_H1F + 262144;          // ~9.2 MB
static constexpr size_t OFF_X0    = WS_BASE;                   // f16 [T][B][2048] (x@Wih0^T + b0)
static constexpr size_t X0_SZ     = (size_t)T_ * 128 * 2048 * 2;
static constexpr size_t WS_PRE    = OFF_X0 + X0_SZ;            // ~265 MB

// ---- agent-scope (mall-coherent) access helpers: no fences anywhere ----
__device__ __forceinline__ f16x8 ld_agent16(const uint32_t* q) {
    uint32_t w0 = __hip_atomic_load(q + 0, __ATOMIC_RELAXED, __HIP_MEMORY_SCOPE_AGENT);
    uint32_t w1 = __hip_atomic_load(q + 1, __ATOMIC_RELAXED, __HIP_MEMORY_SCOPE_AGENT);
    uint32_t w2 = __hip_atomic_load(q + 2, __ATOMIC_RELAXED, __HIP_MEMORY_SCOPE_AGENT);
    uint32_t w3 = __hip_atomic_load(q + 3, __ATOMIC_RELAXED, __HIP_MEMORY_SCOPE_AGENT);
    union { uint32_t u[4]; f16x8 v; } r;
    r.u[0] = w0; r.u[1] = w1; r.u[2] = w2; r.u[3] = w3;
    return r.v;
}

// ---- fence-free sub-grid barrier (h data is agent-coherent per-access) ----
// __syncthreads drains each wave's vmcnt (atomic stores ack'd at mall) before thread0 arrives.
__device__ __forceinline__ void gridbar(int* bar, int nb, int it) {
    __syncthreads();
    if (threadIdx.x == 0) {
        int a = __hip_atomic_fetch_add(&bar[0], 1, __ATOMIC_RELAXED, __HIP_MEMORY_SCOPE_AGENT);
        if (a == nb * (it + 1) - 1) {
            __hip_atomic_store(&bar[16], it + 1, __ATOMIC_RELAXED, __HIP_MEMORY_SCOPE_AGENT);
        } else {
            while (__hip_atomic_load(&bar[16], __ATOMIC_RELAXED, __HIP_MEMORY_SCOPE_AGENT) < it + 1)
                __builtin_amdgcn_s_sleep(1);
        }
    }
    __syncthreads();
}

// ---------------- lengths ----------------
__global__ __launch_bounds__(512) void k_len(const float* __restrict__ x, int* __restrict__ len) {
    int b = blockIdx.x;
    const float4* row = (const float4*)(x + ((size_t)b * T_ + threadIdx.x) * I_);
    float s = 0.f;
    #pragma unroll 4
    for (int i = 0; i < I_ / 4; ++i) { float4 v = row[i]; s += v.x + v.y + v.z + v.w; }
    int cnt = __syncthreads_count(s != 0.0f);
    if (threadIdx.x == 0) len[b] = cnt;
}

// ---------------- weight convert ----------------
__global__ __launch_bounds__(256) void k_wcvt(const float* __restrict__ wih, const float* __restrict__ whh,
                                              const float* __restrict__ bih, const float* __restrict__ bhh,
                                              f16* __restrict__ W, float* __restrict__ bias) {
    int r = blockIdx.x;          // reordered row = u*4+g
    int h = r >> 2, g = r & 3;
    int src = g * 512 + h;
    const float* a = wih + (size_t)src * 512;
    const float* bsrc = whh + (size_t)src * 512;
    f16* dst = W + (size_t)r * 1024;
    #pragma unroll
    for (int j = 0; j < 2; ++j) {
        int k = threadIdx.x + j * 256;
        dst[k]       = (f16)a[k];
        dst[k + 512] = (f16)bsrc[k];
    }
    if (threadIdx.x == 0) bias[r] = bih[src] + bhh[src];
}

// ---------------- X0 precompute ----------------
__global__ __launch_bounds__(256) void k_xgemm(const float* __restrict__ x, const f16* __restrict__ W0,
                                               const float* __restrict__ bias0, f16* __restrict__ X0) {
    __shared__ char lds[65536];
    const int cg = blockIdx.x, b = blockIdx.y, tc = blockIdx.z;
    const int tid = threadIdx.x;
    const int wv = tid >> 6, lane = tid & 63;
    const int l16 = lane & 15, l4 = lane >> 4;
    const int nf = wv;
    {
        const int r = tid >> 2, e = tid & 3;
        const f16* src = W0 + (size_t)(cg * 64 + r) * 1024 + e * 128;
        char* rowp = lds + r * 1024;
        const int sw = (r & 7) << 4;
        #pragma unroll
        for (int j = 0; j < 16; ++j) {
            const int byte = e * 256 + j * 16;
            *(f16x8*)(rowp + (byte ^ sw)) = *(const f16x8*)(src + j * 8);
        }
    }
    __syncthreads();
    const int row_l = nf * 16 + l16;
    const char* Wrow = lds + row_l * 1024;
    const int wsw = (row_l & 7) << 4;
    const int koff = l4 * 8;
    f32x4 acc[8] = {};
    #pragma unroll 4
    for (int ks = 0; ks < 16; ++ks) {
        f16x8 aw = *(const f16x8*)(Wrow + (((ks * 32 + koff) * 2) ^ wsw));
        #pragma unroll
        for (int mf = 0; mf < 8; ++mf) {
            const int tt = tc * 128 + mf * 16 + l16;
            const float* xp = x + ((size_t)b * 512 + tt) * 512 + ks * 32 + koff;
            const float4 p0 = *(const float4*)xp;
            const float4 p1 = *(const float4*)(xp + 4);
            f16x8 v = { (f16)p0.x,(f16)p0.y,(f16)p0.z,(f16)p0.w,
                        (f16)p1.x,(f16)p1.y,(f16)p1.z,(f16)p1.w };
            acc[mf] = __builtin_amdgcn_mfma_f32_16x16x32_f16(aw, v, acc[mf], 0, 0, 0);
        }
    }
    const float4 b4 = *(const float4*)(bias0 + cg * 64 + nf * 16 + l4 * 4);
    const float bb[4] = { b4.x, b4.y, b4.z, b4.w };
    #pragma unroll
    for (int mf = 0; mf < 8; ++mf) {
        const int tt = tc * 128 + mf * 16 + l16;
        f16x4 v;
        #pragma unroll
        for (int g = 0; g < 4; ++g) v[g] = (f16)(acc[mf][g] + bb[g]);
        *(f16x4*)(X0 + ((size_t)tt * 128 + b) * 2048 + cg * 64 + nf * 16 + l4 * 4) = v;
    }
}

// ---------------- persistent kernel ----------------
// 128 blocks x 512 thr. Block = layer (bid>>6) x bg (bid>>5)&1 x cg (bid&31).
// Waves: mf = wv>>1 (4 batch-frags of 16), kh = wv&1 (K-half). Split-K: each activation
// word loaded once per block via agent-scope 4B atomic loads; partials pair-reduced in LDS.
// h exchange: agent-scope 4B atomic stores (u-pairs packed via shfl). Two 64-block
// sub-barriers (per bg), no fences.
__global__ __launch_bounds__(512) void k_persist(
    const float* __restrict__ x,
    const f16* __restrict__ W0, const f16* __restrict__ W1,
    const float* __restrict__ bias0, const float* __restrict__ bias1,
    const int* __restrict__ len,
    f16* __restrict__ h0a, f16* __restrict__ h0b,
    f16* __restrict__ h1a, f16* __restrict__ h1b,
    float* __restrict__ h1f,
    const f16* __restrict__ X0, int pre, int* bar)
{
    extern __shared__ char lds[];          // 128K weights + 16K reduce buf
    char* Rbuf = lds + 131072;
    const int tid = threadIdx.x;
    const int bid = blockIdx.x;
    const int layer = bid >> 6;
    const int bg = (bid >> 5) & 1;
    const int cg = bid & 31;
    const int wv = tid >> 6, lane = tid & 63;
    const int mf = wv >> 1, kh = wv & 1;
    const int l16 = lane & 15, l4 = lane >> 4;
    int* mybar = bar + bg * 32;

    {   // one-off weight staging (64 rows x 1024 K, 16B-granule XOR swizzle)
        const f16* Wsrc = (layer ? W1 : W0) + (size_t)(cg * 64) * 1024;
        const int r = tid >> 3, e = tid & 7;
        const f16* src = Wsrc + (size_t)r * 1024 + e * 128;
        char* rowp = lds + r * 2048;
        const int sw = (r & 7) << 4;
        #pragma unroll
        for (int j = 0; j < 16; ++j) {
            const int byte = e * 256 + j * 16;
            *(f16x8*)(rowp + (byte ^ sw)) = *(const f16x8*)(src + j * 8);
        }
    }

    const int bb = bg * 64 + mf * 16 + l16;        // this lane's batch (B-frag col)
    const int ubase = cg * 16;
    const int wsw = (l16 & 7) << 4;                // row swizzle (same for all nf)
    const char* Wr0 = lds + (0 * 16 + l16) * 2048;
    const char* Wr1 = lds + (1 * 16 + l16) * 2048;
    const char* Wr2 = lds + (2 * 16 + l16) * 2048;
    const char* Wr3 = lds + (3 * 16 + l16) * 2048;
    const int lb = len[bb];
    float4 bias4[4];
    #pragma unroll
    for (int nf = 0; nf < 4; ++nf) {
        if (layer) bias4[nf] = *(const float4*)(bias1 + (ubase + nf * 4 + l4) * 4);
        else if (!pre) bias4[nf] = *(const float4*)(bias0 + (ubase + nf * 4 + l4) * 4);
        else bias4[nf] = make_float4(0.f, 0.f, 0.f, 0.f);
    }
    float c_s[4] = {0.f, 0.f, 0.f, 0.f};
    f16 h_s[4] = {(f16)0.f, (f16)0.f, (f16)0.f, (f16)0.f};

    __syncthreads();

    for (int t = 0; t <= T_; ++t) {
        const int step = layer ? (t - 1) : t;
        const bool active = (step >= 0) && (step < T_);
        if (active) {
            f32x4 acc[4] = {};
            const int u32base = bb * 256 + l4 * 4;    // u32 index of lane's 16B row chunk

            if (layer == 0) {
                const f16* hprev = (t & 1) ? h0a : h0b;            // h0(t-1)
                const uint32_t* hpu = (const uint32_t*)hprev + u32base;
                if (pre) {
                    // live K = 512 (hh); kh halves it: ks 8 each
                    const int kbase = kh * 256;
                    #pragma unroll
                    for (int ks = 0; ks < 8; ++ks) {
                        f16x8 v = ld_agent16(hpu + kbase / 2 + ks * 16);
                        const int kb = (512 + kbase + ks * 32 + l4 * 8) * 2;
                        acc[0] = __builtin_amdgcn_mfma_f32_16x16x32_f16(*(const f16x8*)(Wr0 + (kb ^ wsw)), v, acc[0], 0, 0, 0);
                        acc[1] = __builtin_amdgcn_mfma_f32_16x16x32_f16(*(const f16x8*)(Wr1 + (kb ^ wsw)), v, acc[1], 0, 0, 0);
                        acc[2] = __builtin_amdgcn_mfma_f32_16x16x32_f16(*(const f16x8*)(Wr2 + (kb ^ wsw)), v, acc[2], 0, 0, 0);
                        acc[3] = __builtin_amdgcn_mfma_f32_16x16x32_f16(*(const f16x8*)(Wr3 + (kb ^ wsw)), v, acc[3], 0, 0, 0);
                    }
                } else if (kh == 0) {
                    // ih on x (f32 -> f16), full K=512
                    const float* xp = x + ((size_t)bb * 512 + t) * 512 + l4 * 8;
                    #pragma unroll
                    for (int ks = 0; ks < 16; ++ks) {
                        const float4 p0 = *(const float4*)(xp + ks * 32);
                        const float4 p1 = *(const float4*)(xp + ks * 32 + 4);
                        f16x8 v = { (f16)p0.x,(f16)p0.y,(f16)p0.z,(f16)p0.w,
                                    (f16)p1.x,(f16)p1.y,(f16)p1.z,(f16)p1.w };
                        const int kb = (ks * 32 + l4 * 8) * 2;
                        acc[0] = __builtin_amdgcn_mfma_f32_16x16x32_f16(*(const f16x8*)(Wr0 + (kb ^ wsw)), v, acc[0], 0, 0, 0);
                        acc[1] = __builtin_amdgcn_mfma_f32_16x16x32_f16(*(const f16x8*)(Wr1 + (kb ^ wsw)), v, acc[1], 0, 0, 0);
                        acc[2] = __builtin_amdgcn_mfma_f32_16x16x32_f16(*(const f16x8*)(Wr2 + (kb ^ wsw)), v, acc[2], 0, 0, 0);
                        acc[3] = __builtin_amdgcn_mfma_f32_16x16x32_f16(*(const f16x8*)(Wr3 + (kb ^ wsw)), v, acc[3], 0, 0, 0);
                    }
                } else {
                    // hh on h0(t-1), full K=512
                    #pragma unroll
                    for (int ks = 0; ks < 16; ++ks) {
                        f16x8 v = ld_agent16(hpu + ks * 16);
                        const int kb = (512 + ks * 32 + l4 * 8) * 2;
                        acc[0] = __builtin_amdgcn_mfma_f32_16x16x32_f16(*(const f16x8*)(Wr0 + (kb ^ wsw)), v, acc[0], 0, 0, 0);
                        acc[1] = __builtin_amdgcn_mfma_f32_16x16x32_f16(*(const f16x8*)(Wr1 + (kb ^ wsw)), v, acc[1], 0, 0, 0);
                        acc[2] = __builtin_amdgcn_mfma_f32_16x16x32_f16(*(const f16x8*)(Wr2 + (kb ^ wsw)), v, acc[2], 0, 0, 0);
                        acc[3] = __builtin_amdgcn_mfma_f32_16x16x32_f16(*(const f16x8*)(Wr3 + (kb ^ wsw)), v, acc[3], 0, 0, 0);
                    }
                }
            } else {
                const int s = step;
                const f16* src = (kh == 0) ? ((s & 1) ? h0b : h0a)     // ih: h0(s)
                                           : ((s & 1) ? h1a : h1b);    // hh: h1(s-1)
                const uint32_t* hpu = (const uint32_t*)src + u32base;
                const int wseg = kh ? 1024 : 0;                        // byte offset of K-segment
                #pragma unroll
                for (int ks = 0; ks < 16; ++ks) {
                    f16x8 v = ld_agent16(hpu + ks * 16);
                    const int kb = wseg + (ks * 32 + l4 * 8) * 2;
                    acc[0] = __builtin_amdgcn_mfma_f32_16x16x32_f16(*(const f16x8*)(Wr0 + (kb ^ wsw)), v, acc[0], 0, 0, 0);
                    acc[1] = __builtin_amdgcn_mfma_f32_16x16x32_f16(*(const f16x8*)(Wr1 + (kb ^ wsw)), v, acc[1], 0, 0, 0);
                    acc[2] = __builtin_amdgcn_mfma_f32_16x16x32_f16(*(const f16x8*)(Wr2 + (kb ^ wsw)), v, acc[2], 0, 0, 0);
                    acc[3] = __builtin_amdgcn_mfma_f32_16x16x32_f16(*(const f16x8*)(Wr3 + (kb ^ wsw)), v, acc[3], 0, 0, 0);
                }
            }

            // pair-reduce kh partials through LDS
            if (kh == 1) {
                #pragma unroll
                for (int nf = 0; nf < 4; ++nf)
                    *(f32x4*)(Rbuf + ((mf * 4 + nf) * 64 + lane) * 16) = acc[nf];
            }
            __syncthreads();
            if (kh == 0) {
                #pragma unroll
                for (int nf = 0; nf < 4; ++nf) {
                    const f32x4 o = *(const f32x4*)(Rbuf + ((mf * 4 + nf) * 64 + lane) * 16);
                    acc[nf] += o;
                }
                // epilogue: lane owns units ubase+nf*4+l4, batch bb
                f16* hw;
                if (layer == 0) hw = (t & 1) ? h0b : h0a;              // h0(t)
                else            hw = (step & 1) ? h1b : h1a;           // h1(s)
                const bool msk = step < lb;
                #pragma unroll
                for (int nf = 0; nf < 4; ++nf) {
                    const int u = ubase + nf * 4 + l4;
                    float xg0, xg1, xg2, xg3;
                    if (layer == 0 && pre) {
                        const f16x4 xa = *(const f16x4*)(X0 + ((size_t)t * 128 + bb) * 2048 + u * 4);
                        xg0 = (float)xa[0]; xg1 = (float)xa[1]; xg2 = (float)xa[2]; xg3 = (float)xa[3];
                    } else {
                        xg0 = bias4[nf].x; xg1 = bias4[nf].y; xg2 = bias4[nf].z; xg3 = bias4[nf].w;
                    }
                    const float gi = acc[nf][0] + xg0, gf = acc[nf][1] + xg1;
                    const float gg = acc[nf][2] + xg2, go = acc[nf][3] + xg3;
                    const float cn = (1.f / (1.f + expf(-gf))) * c_s[nf]
                                   + (1.f / (1.f + expf(-gi))) * tanhf(gg);
                    const float hn = (1.f / (1.f + expf(-go))) * tanhf(cn);
                    if (msk) { c_s[nf] = cn; h_s[nf] = (f16)hn; }
                    // pack u-pairs (l4 even with l4+1) and agent-store 4B
                    union { f16 h; uint16_t u16; } cv; cv.h = h_s[nf];
                    const int pb = __shfl_xor((int)cv.u16, 16);
                    if ((l4 & 1) == 0) {
                        const uint32_t w = (uint32_t)cv.u16 | ((uint32_t)(uint16_t)pb << 16);
                        __hip_atomic_store((uint32_t*)(hw + (size_t)bb * 512 + u), w,
                                           __ATOMIC_RELAXED, __HIP_MEMORY_SCOPE_AGENT);
                    }
                    if (layer && msk) h1f[(size_t)bb * 512 + u] = hn;
                }
            }
        }
        gridbar(mybar, NBLK / 2, t);
    }
}

// ---------------- final FC ----------------
__global__ __launch_bounds__(256) void k_fc(const float* __restrict__ h1f,
                                            const float* __restrict__ wfc,
                                            const float* __restrict__ bfc,
                                            float* __restrict__ out) {
    int b = blockIdx.x;
    float s0 = 0, s1 = 0, s2 = 0, s3 = 0;
    for (int h = threadIdx.x; h < 512; h += 256) {
        float v = h1f[(size_t)b * 512 + h];
        s0 += v * wfc[h];
        s1 += v * wfc[512 + h];
        s2 += v * wfc[1024 + h];
        s3 += v * wfc[1536 + h];
    }
    #pragma unroll
    for (int off = 32; off; off >>= 1) {
        s0 += __shfl_down(s0, off);
        s1 += __shfl_down(s1, off);
        s2 += __shfl_down(s2, off);
        s3 += __shfl_down(s3, off);
    }
    __shared__ float red[4][4];
    int wid = threadIdx.x >> 6;
    if ((threadIdx.x & 63) == 0) { red[wid][0] = s0; red[wid][1] = s1; red[wid][2] = s2; red[wid][3] = s3; }
    __syncthreads();
    if (threadIdx.x < 4) {
        float s = red[0][threadIdx.x] + red[1][threadIdx.x] + red[2][threadIdx.x] + red[3][threadIdx.x]
                + bfc[threadIdx.x];
        out[b * 4 + threadIdx.x] = s;
    }
}

extern "C" void kernel_launch(void* const* d_in, const int* in_sizes, int n_in,
                              void* d_out, int out_size, void* d_ws, size_t ws_size,
                              hipStream_t stream) {
    const float* x    = (const float*)d_in[0];
    const float* wih0 = (const float*)d_in[1];
    const float* whh0 = (const float*)d_in[2];
    const float* bih0 = (const float*)d_in[3];
    const float* bhh0 = (const float*)d_in[4];
    const float* wih1 = (const float*)d_in[5];
    const float* whh1 = (const float*)d_in[6];
    const float* bih1 = (const float*)d_in[7];
    const float* bhh1 = (const float*)d_in[8];
    const float* wfc  = (const float*)d_in[9];
    const float* bfc  = (const float*)d_in[10];

    if (ws_size < WS_BASE) return;
    const int pre = (ws_size >= WS_PRE) ? 1 : 0;

    char* ws = (char*)d_ws;
    int*   bar   = (int*)(ws + OFF_BAR);
    int*   len   = (int*)(ws + OFF_LEN);
    float* bias0 = (float*)(ws + OFF_BIAS0);
    float* bias1 = (float*)(ws + OFF_BIAS1);
    f16*   W0    = (f16*)(ws + OFF_W0);
    f16*   W1    = (f16*)(ws + OFF_W1);
    f16*   h0a   = (f16*)(ws + OFF_H0A);
    f16*   h0b   = (f16*)(ws + OFF_H0B);
    f16*   h1a   = (f16*)(ws + OFF_H1A);
    f16*   h1b   = (f16*)(ws + OFF_H1B);
    float* h1f   = (float*)(ws + OFF_H1F);
    f16*   X0p   = (f16*)(ws + OFF_X0);

    hipMemsetAsync(ws + OFF_BAR, 0, 512, stream);
    hipMemsetAsync(ws + OFF_H0A, 0, WS_BASE - OFF_H0A, stream);

    k_len<<<B_, 512, 0, stream>>>(x, len);
    k_wcvt<<<2048, 256, 0, stream>>>(wih0, whh0, bih0, bhh0, W0, bias0);
    k_wcvt<<<2048, 256, 0, stream>>>(wih1, whh1, bih1, bhh1, W1, bias1);
    if (pre) k_xgemm<<<dim3(32, 128, 4), 256, 0, stream>>>(x, W0, bias0, X0p);

    hipFuncSetAttribute((const void*)k_persist, hipFuncAttributeMaxDynamicSharedMemorySize, 147456);
    const f16* X0c = X0p;
    void* kargs[] = {
        (void*)&x, (void*)&W0, (void*)&W1, (void*)&bias0, (void*)&bias1, (void*)&len,
        (void*)&h0a, (void*)&h0b, (void*)&h1a, (void*)&h1b, (void*)&h1f,
        (void*)&X0c, (void*)&pre, (void*)&bar
    };
    hipLaunchCooperativeKernel((const void*)k_persist, dim3(NBLK), dim3(512),
                               kargs, 147456, stream);

    k_fc<<<B_, 256, 0, stream>>>(h1f, wfc, bfc, (float*)d_out);
}

// Round 5
// 7891.828 us; speedup vs baseline: 2.4902x; 1.5328x over previous
//
#include <hip/hip_runtime.h>
#include <hip/hip_fp16.h>

typedef _Float16 f16;
typedef _Float16 f16x8 __attribute__((ext_vector_type(8)));
typedef _Float16 f16x4 __attribute__((ext_vector_type(4)));
typedef float f32x4 __attribute__((ext_vector_type(4)));

#define B_ 128
#define T_ 512
#define I_ 512
#define H_ 512
#define NBLK 128

// ---------------- workspace layout (bytes) ----------------
static constexpr size_t OFF_BAR   = 0;                         // slots[2][64] + rel[2]
static constexpr size_t OFF_LEN   = 1024;                      // 128 int
static constexpr size_t OFF_BIAS0 = 2048;                      // 2048 f32
static constexpr size_t OFF_BIAS1 = 10240;                     // 2048 f32
static constexpr size_t OFF_W0    = 32768;                     // 2048x1024 f16, rows u*4+g, [w_ih|w_hh]
static constexpr size_t OFF_W1    = OFF_W0 + 4u*1024u*1024u;
static constexpr size_t OFF_H0A   = OFF_W1 + 4u*1024u*1024u;   // 128x512 f16 each
static constexpr size_t OFF_H0B   = OFF_H0A + 131072;
static constexpr size_t OFF_H1A   = OFF_H0B + 131072;
static constexpr size_t OFF_H1B   = OFF_H1A + 131072;
static constexpr size_t OFF_H1F   = OFF_H1B + 131072;          // 128x512 f32
static constexpr size_t WS_BASE   = OFF_H1F + 262144;
static constexpr size_t OFF_X0    = WS_BASE;                   // f16 [T][B][2048]
static constexpr size_t X0_SZ     = (size_t)T_ * 128 * 2048 * 2;
static constexpr size_t WS_PRE    = OFF_X0 + X0_SZ;

// ---- batched mall-coherent load blobs (bypass L1+L2 via sc0 sc1) ----
__device__ __forceinline__ void ldblob16(const void* p, f16x8* v) {
    asm volatile(
        "global_load_dwordx4 %0, %16, off offset:0 sc0 sc1\n\t"
        "global_load_dwordx4 %1, %16, off offset:64 sc0 sc1\n\t"
        "global_load_dwordx4 %2, %16, off offset:128 sc0 sc1\n\t"
        "global_load_dwordx4 %3, %16, off offset:192 sc0 sc1\n\t"
        "global_load_dwordx4 %4, %16, off offset:256 sc0 sc1\n\t"
        "global_load_dwordx4 %5, %16, off offset:320 sc0 sc1\n\t"
        "global_load_dwordx4 %6, %16, off offset:384 sc0 sc1\n\t"
        "global_load_dwordx4 %7, %16, off offset:448 sc0 sc1\n\t"
        "global_load_dwordx4 %8, %16, off offset:512 sc0 sc1\n\t"
        "global_load_dwordx4 %9, %16, off offset:576 sc0 sc1\n\t"
        "global_load_dwordx4 %10, %16, off offset:640 sc0 sc1\n\t"
        "global_load_dwordx4 %11, %16, off offset:704 sc0 sc1\n\t"
        "global_load_dwordx4 %12, %16, off offset:768 sc0 sc1\n\t"
        "global_load_dwordx4 %13, %16, off offset:832 sc0 sc1\n\t"
        "global_load_dwordx4 %14, %16, off offset:896 sc0 sc1\n\t"
        "global_load_dwordx4 %15, %16, off offset:960 sc0 sc1"
        : "=&v"(v[0]), "=&v"(v[1]), "=&v"(v[2]), "=&v"(v[3]),
          "=&v"(v[4]), "=&v"(v[5]), "=&v"(v[6]), "=&v"(v[7]),
          "=&v"(v[8]), "=&v"(v[9]), "=&v"(v[10]), "=&v"(v[11]),
          "=&v"(v[12]), "=&v"(v[13]), "=&v"(v[14]), "=&v"(v[15])
        : "v"(p) : "memory");
}
__device__ __forceinline__ void ldblob8(const void* p, f16x8* v) {
    asm volatile(
        "global_load_dwordx4 %0, %8, off offset:0 sc0 sc1\n\t"
        "global_load_dwordx4 %1, %8, off offset:64 sc0 sc1\n\t"
        "global_load_dwordx4 %2, %8, off offset:128 sc0 sc1\n\t"
        "global_load_dwordx4 %3, %8, off offset:192 sc0 sc1\n\t"
        "global_load_dwordx4 %4, %8, off offset:256 sc0 sc1\n\t"
        "global_load_dwordx4 %5, %8, off offset:320 sc0 sc1\n\t"
        "global_load_dwordx4 %6, %8, off offset:384 sc0 sc1\n\t"
        "global_load_dwordx4 %7, %8, off offset:448 sc0 sc1"
        : "=&v"(v[0]), "=&v"(v[1]), "=&v"(v[2]), "=&v"(v[3]),
          "=&v"(v[4]), "=&v"(v[5]), "=&v"(v[6]), "=&v"(v[7])
        : "v"(p) : "memory");
}
__device__ __forceinline__ void waitvm0() {
    asm volatile("s_waitcnt vmcnt(0)" ::: "memory");
    __builtin_amdgcn_sched_barrier(0);
}

// ---------------- lengths: count rows with sum != 0 ----------------
__global__ __launch_bounds__(512) void k_len(const float* __restrict__ x, int* __restrict__ len) {
    int b = blockIdx.x, q = blockIdx.y;
    int rl = threadIdx.x >> 2, part = threadIdx.x & 3;
    const float4* p = (const float4*)(x + ((size_t)b * T_ + q * 128 + rl) * I_ + part * 128);
    float s = 0.f;
    #pragma unroll
    for (int i = 0; i < 32; ++i) { float4 v = p[i]; s += v.x + v.y + v.z + v.w; }
    s += __shfl_xor(s, 1);
    s += __shfl_xor(s, 2);
    int cnt = __syncthreads_count(part == 0 && s != 0.0f);
    if (threadIdx.x == 0) atomicAdd(&len[b], cnt);
}

// ---------------- weight convert: rows u*4+gate, concat [w_ih|w_hh], f32->f16 ----------------
__global__ __launch_bounds__(256) void k_wcvt(const float* __restrict__ wih, const float* __restrict__ whh,
                                              const float* __restrict__ bih, const float* __restrict__ bhh,
                                              f16* __restrict__ W, float* __restrict__ bias) {
    int r = blockIdx.x;          // reordered row = u*4+g
    int h = r >> 2, g = r & 3;
    int src = g * 512 + h;
    const float* a = wih + (size_t)src * 512;
    const float* bsrc = whh + (size_t)src * 512;
    f16* dst = W + (size_t)r * 1024;
    #pragma unroll
    for (int j = 0; j < 2; ++j) {
        int k = threadIdx.x + j * 256;
        dst[k]       = (f16)a[k];
        dst[k + 512] = (f16)bsrc[k];
    }
    if (threadIdx.x == 0) bias[r] = bih[src] + bhh[src];
}

// ---------------- X0 precompute: X0[t][b][:] = x[b][t][:] @ w_ih0^T + b0 ----------------
__global__ __launch_bounds__(256) void k_xgemm(const float* __restrict__ x, const f16* __restrict__ W0,
                                               const float* __restrict__ bias0, f16* __restrict__ X0) {
    __shared__ char lds[65536];
    const int cg = blockIdx.x, b = blockIdx.y, tc = blockIdx.z;
    const int tid = threadIdx.x;
    const int wv = tid >> 6, lane = tid & 63;
    const int l16 = lane & 15, l4 = lane >> 4;
    const int nf = wv;
    {
        const int r = tid >> 2, e = tid & 3;
        const f16* src = W0 + (size_t)(cg * 64 + r) * 1024 + e * 128;
        char* rowp = lds + r * 1024;
        const int sw = (r & 7) << 4;
        #pragma unroll
        for (int j = 0; j < 16; ++j) {
            const int byte = e * 256 + j * 16;
            *(f16x8*)(rowp + (byte ^ sw)) = *(const f16x8*)(src + j * 8);
        }
    }
    __syncthreads();
    const int row_l = nf * 16 + l16;
    const char* Wrow = lds + row_l * 1024;
    const int wsw = (row_l & 7) << 4;
    const int koff = l4 * 8;
    f32x4 acc[8] = {};
    #pragma unroll 4
    for (int ks = 0; ks < 16; ++ks) {
        f16x8 aw = *(const f16x8*)(Wrow + (((ks * 32 + koff) * 2) ^ wsw));
        #pragma unroll
        for (int mf = 0; mf < 8; ++mf) {
            const int tt = tc * 128 + mf * 16 + l16;
            const float* xp = x + ((size_t)b * 512 + tt) * 512 + ks * 32 + koff;
            const float4 p0 = *(const float4*)xp;
            const float4 p1 = *(const float4*)(xp + 4);
            f16x8 v = { (f16)p0.x,(f16)p0.y,(f16)p0.z,(f16)p0.w,
                        (f16)p1.x,(f16)p1.y,(f16)p1.z,(f16)p1.w };
            acc[mf] = __builtin_amdgcn_mfma_f32_16x16x32_f16(aw, v, acc[mf], 0, 0, 0);
        }
    }
    const float4 b4 = *(const float4*)(bias0 + cg * 64 + nf * 16 + l4 * 4);
    const float bb[4] = { b4.x, b4.y, b4.z, b4.w };
    #pragma unroll
    for (int mf = 0; mf < 8; ++mf) {
        const int tt = tc * 128 + mf * 16 + l16;
        f16x4 v;
        #pragma unroll
        for (int g = 0; g < 4; ++g) v[g] = (f16)(acc[mf][g] + bb[g]);
        *(f16x4*)(X0 + ((size_t)tt * 128 + b) * 2048 + cg * 64 + nf * 16 + l4 * 4) = v;
    }
}

// ---------------- persistent kernel ----------------
// 128 blocks x 512 thr. Block = layer (bid>>6) x bg (bid>>5)&1 x cg (bid&31).
// Waves: kh = wv&1 (K-half/operand), mfg = (wv>>1)&1 (32 batches), nfg = wv>>2 (8 units).
// Weights in LDS in fragment-major order (conflict-free ds_read_b128, imm offsets).
// h loads: one asm blob of mall-coherent dwordx4 per wave (single round trip).
// Barrier: arrival slots (plain agent stores) + aggregator wave + release flag. No fences.
__global__ __launch_bounds__(512) void k_persist(
    const float* __restrict__ x,
    const f16* __restrict__ W0, const f16* __restrict__ W1,
    const float* __restrict__ bias0, const float* __restrict__ bias1,
    const int* __restrict__ len,
    f16* __restrict__ h0a, f16* __restrict__ h0b,
    f16* __restrict__ h1a, f16* __restrict__ h1b,
    float* __restrict__ h1f,
    const f16* __restrict__ X0, int pre, int* bar)
{
    extern __shared__ char lds[];          // 128K weights (frag-major) + 16K reduce buf
    char* Rbuf = lds + 131072;
    const int tid = threadIdx.x;
    const int bid = blockIdx.x;
    const int layer = bid >> 6;
    const int bg = (bid >> 5) & 1;
    const int cg = bid & 31;
    const int wv = tid >> 6, lane = tid & 63;
    const int kh = wv & 1, mfg = (wv >> 1) & 1, nfg = wv >> 2;
    const int l16 = lane & 15, l4 = lane >> 4;

    int* slots = bar + bg * 64;
    int* rel   = bar + 128 + bg * 16;
    const int  sidx  = layer * 32 + cg;
    const bool isagg = (layer == 0) && (cg == 0);

    // ---- stage weights into LDS, fragment-major: frag f = (k>>9)*64 + ((k>>5)&15)*4 + (r>>4)
    //      byte = f*1024 + (((k>>3)&3)*16 + (r&15))*16 + (k&7)*2
    {
        const f16* Wsrc = (layer ? W1 : W0) + (size_t)(cg * 64) * 1024;
        #pragma unroll
        for (int j = 0; j < 16; ++j) {
            int cid = j * 512 + tid;               // 8192 16B-chunks: r = cid>>7, kc = cid&127
            int r = cid >> 7, kc = cid & 127;
            f16x8 w = *(const f16x8*)(Wsrc + (size_t)r * 1024 + kc * 8);
            int f = (kc >> 6) * 64 + ((kc >> 2) & 15) * 4 + (r >> 4);
            *(f16x8*)(lds + f * 1024 + ((kc & 3) * 16 + (r & 15)) * 16) = w;
        }
    }

    const int bbA = bg * 64 + mfg * 32 + l16;      // batches (two m-frags per wave)
    const int bbB = bbA + 16;
    const int lbA = len[bbA], lbB = len[bbB];
    float4 bias4[2];
    #pragma unroll
    for (int ni = 0; ni < 2; ++ni) {
        const int u = cg * 16 + (nfg * 2 + ni) * 4 + l4;
        if (layer) bias4[ni] = *(const float4*)(bias1 + u * 4);
        else if (!pre) bias4[ni] = *(const float4*)(bias0 + u * 4);
        else bias4[ni] = make_float4(0.f, 0.f, 0.f, 0.f);
    }
    float c_s[2][2] = {};
    f16 h_s[2][2] = {};

    __syncthreads();

    for (int t = 0; t <= T_; ++t) {
        const int step = layer ? (t - 1) : t;
        const bool active = (step >= 0) && (step < T_);
        if (active) {
            f32x4 acc[2][2] = {};
            f16x8 hvA[16], hvB[16];
            f16x4 x0v[2][2];

            if (layer == 0) {
                const f16* hprev = (t & 1) ? h0a : h0b;              // h0(t-1)
                if (pre) {
                    if (kh == 0) {                                    // prefetch X0 for epilogue
                        #pragma unroll
                        for (int mi = 0; mi < 2; ++mi)
                            #pragma unroll
                            for (int ni = 0; ni < 2; ++ni)
                                x0v[mi][ni] = *(const f16x4*)(X0 + ((size_t)t * 128 + (mi ? bbB : bbA)) * 2048
                                                              + (cg * 16 + (nfg * 2 + ni) * 4 + l4) * 4);
                    }
                    const char* pA = (const char*)hprev + bbA * 1024 + kh * 512 + l4 * 16;
                    const char* pB = (const char*)hprev + bbB * 1024 + kh * 512 + l4 * 16;
                    ldblob8(pA, hvA);
                    ldblob8(pB, hvB);
                    waitvm0();
                    const char* wb = lds + (64 + kh * 32 + nfg * 2) * 1024 + lane * 16;
                    #pragma unroll
                    for (int ks = 0; ks < 8; ++ks) {
                        f16x8 w0 = *(const f16x8*)(wb + (ks * 4 + 0) * 1024);
                        f16x8 w1 = *(const f16x8*)(wb + (ks * 4 + 1) * 1024);
                        acc[0][0] = __builtin_amdgcn_mfma_f32_16x16x32_f16(w0, hvA[ks], acc[0][0], 0, 0, 0);
                        acc[0][1] = __builtin_amdgcn_mfma_f32_16x16x32_f16(w1, hvA[ks], acc[0][1], 0, 0, 0);
                        acc[1][0] = __builtin_amdgcn_mfma_f32_16x16x32_f16(w0, hvB[ks], acc[1][0], 0, 0, 0);
                        acc[1][1] = __builtin_amdgcn_mfma_f32_16x16x32_f16(w1, hvB[ks], acc[1][1], 0, 0, 0);
                    }
                } else {
                    if (kh == 0) {                                    // ih on x (f32->f16), K=512
                        const float* xp0 = x + ((size_t)bbA * 512 + t) * 512 + l4 * 8;
                        const float* xp1 = x + ((size_t)bbB * 512 + t) * 512 + l4 * 8;
                        const char* wb = lds + (nfg * 2) * 1024 + lane * 16;
                        #pragma unroll
                        for (int ks = 0; ks < 16; ++ks) {
                            const float4 p0 = *(const float4*)(xp0 + ks * 32);
                            const float4 p1 = *(const float4*)(xp0 + ks * 32 + 4);
                            const float4 p2 = *(const float4*)(xp1 + ks * 32);
                            const float4 p3 = *(const float4*)(xp1 + ks * 32 + 4);
                            f16x8 vA = { (f16)p0.x,(f16)p0.y,(f16)p0.z,(f16)p0.w,
                                         (f16)p1.x,(f16)p1.y,(f16)p1.z,(f16)p1.w };
                            f16x8 vB = { (f16)p2.x,(f16)p2.y,(f16)p2.z,(f16)p2.w,
                                         (f16)p3.x,(f16)p3.y,(f16)p3.z,(f16)p3.w };
                            f16x8 w0 = *(const f16x8*)(wb + (ks * 4 + 0) * 1024);
                            f16x8 w1 = *(const f16x8*)(wb + (ks * 4 + 1) * 1024);
                            acc[0][0] = __builtin_amdgcn_mfma_f32_16x16x32_f16(w0, vA, acc[0][0], 0, 0, 0);
                            acc[0][1] = __builtin_amdgcn_mfma_f32_16x16x32_f16(w1, vA, acc[0][1], 0, 0, 0);
                            acc[1][0] = __builtin_amdgcn_mfma_f32_16x16x32_f16(w0, vB, acc[1][0], 0, 0, 0);
                            acc[1][1] = __builtin_amdgcn_mfma_f32_16x16x32_f16(w1, vB, acc[1][1], 0, 0, 0);
                        }
                    } else {                                          // hh on h0(t-1), K=512
                        const char* pA = (const char*)hprev + bbA * 1024 + l4 * 16;
                        const char* pB = (const char*)hprev + bbB * 1024 + l4 * 16;
                        ldblob16(pA, hvA);
                        ldblob16(pB, hvB);
                        waitvm0();
                        const char* wb = lds + (64 + nfg * 2) * 1024 + lane * 16;
                        #pragma unroll
                        for (int ks = 0; ks < 16; ++ks) {
                            f16x8 w0 = *(const f16x8*)(wb + (ks * 4 + 0) * 1024);
                            f16x8 w1 = *(const f16x8*)(wb + (ks * 4 + 1) * 1024);
                            acc[0][0] = __builtin_amdgcn_mfma_f32_16x16x32_f16(w0, hvA[ks], acc[0][0], 0, 0, 0);
                            acc[0][1] = __builtin_amdgcn_mfma_f32_16x16x32_f16(w1, hvA[ks], acc[0][1], 0, 0, 0);
                            acc[1][0] = __builtin_amdgcn_mfma_f32_16x16x32_f16(w0, hvB[ks], acc[1][0], 0, 0, 0);
                            acc[1][1] = __builtin_amdgcn_mfma_f32_16x16x32_f16(w1, hvB[ks], acc[1][1], 0, 0, 0);
                        }
                    }
                }
            } else {
                const int s = step;
                const f16* hsrc = (kh == 0) ? ((s & 1) ? h0b : h0a)   // ih: h0(s)
                                            : ((s & 1) ? h1a : h1b);  // hh: h1(s-1)
                const char* pA = (const char*)hsrc + bbA * 1024 + l4 * 16;
                const char* pB = (const char*)hsrc + bbB * 1024 + l4 * 16;
                ldblob16(pA, hvA);
                ldblob16(pB, hvB);
                waitvm0();
                const char* wb = lds + (kh * 64 + nfg * 2) * 1024 + lane * 16;
                #pragma unroll
                for (int ks = 0; ks < 16; ++ks) {
                    f16x8 w0 = *(const f16x8*)(wb + (ks * 4 + 0) * 1024);
                    f16x8 w1 = *(const f16x8*)(wb + (ks * 4 + 1) * 1024);
                    acc[0][0] = __builtin_amdgcn_mfma_f32_16x16x32_f16(w0, hvA[ks], acc[0][0], 0, 0, 0);
                    acc[0][1] = __builtin_amdgcn_mfma_f32_16x16x32_f16(w1, hvA[ks], acc[0][1], 0, 0, 0);
                    acc[1][0] = __builtin_amdgcn_mfma_f32_16x16x32_f16(w0, hvB[ks], acc[1][0], 0, 0, 0);
                    acc[1][1] = __builtin_amdgcn_mfma_f32_16x16x32_f16(w1, hvB[ks], acc[1][1], 0, 0, 0);
                }
            }

            // ---- kh pair-reduce through LDS ----
            if (kh == 1) {
                const int g = wv >> 1;
                #pragma unroll
                for (int mi = 0; mi < 2; ++mi)
                    #pragma unroll
                    for (int ni = 0; ni < 2; ++ni)
                        *(f32x4*)(Rbuf + (((g * 4 + mi * 2 + ni) * 64) + lane) * 16) = acc[mi][ni];
            }
            __syncthreads();
            if (kh == 0) {
                const int g = wv >> 1;
                #pragma unroll
                for (int mi = 0; mi < 2; ++mi)
                    #pragma unroll
                    for (int ni = 0; ni < 2; ++ni)
                        acc[mi][ni] += *(const f32x4*)(Rbuf + (((g * 4 + mi * 2 + ni) * 64) + lane) * 16);

                f16* hw = (layer == 0) ? ((t & 1) ? h0b : h0a)        // h0(t)
                                       : ((step & 1) ? h1b : h1a);    // h1(s)
                #pragma unroll
                for (int mi = 0; mi < 2; ++mi) {
                    const int bb = mi ? bbB : bbA;
                    const int lbv = mi ? lbB : lbA;
                    const bool msk = step < lbv;
                    #pragma unroll
                    for (int ni = 0; ni < 2; ++ni) {
                        const int u = cg * 16 + (nfg * 2 + ni) * 4 + l4;
                        float g0, g1, g2, g3;
                        if (layer == 0 && pre) {
                            g0 = (float)x0v[mi][ni][0]; g1 = (float)x0v[mi][ni][1];
                            g2 = (float)x0v[mi][ni][2]; g3 = (float)x0v[mi][ni][3];
                        } else {
                            g0 = bias4[ni].x; g1 = bias4[ni].y; g2 = bias4[ni].z; g3 = bias4[ni].w;
                        }
                        const float gi = acc[mi][ni][0] + g0, gf = acc[mi][ni][1] + g1;
                        const float gg = acc[mi][ni][2] + g2, go = acc[mi][ni][3] + g3;
                        const float cn = (1.f / (1.f + expf(-gf))) * c_s[mi][ni]
                                       + (1.f / (1.f + expf(-gi))) * tanhf(gg);
                        const float hn = (1.f / (1.f + expf(-go))) * tanhf(cn);
                        if (msk) { c_s[mi][ni] = cn; h_s[mi][ni] = (f16)hn; }
                        union { f16 h; uint16_t u16; } cv; cv.h = h_s[mi][ni];
                        const int pb = __shfl_xor((int)cv.u16, 16);
                        if ((l4 & 1) == 0) {
                            const uint32_t w = (uint32_t)cv.u16 | ((uint32_t)(uint16_t)pb << 16);
                            __hip_atomic_store((uint32_t*)(hw + (size_t)bb * 512 + u), w,
                                               __ATOMIC_RELAXED, __HIP_MEMORY_SCOPE_AGENT);
                        }
                        if (layer == 1 && step == lbv - 1) h1f[(size_t)bb * 512 + u] = hn;
                    }
                }
            }
        }

        // ---- no-RMW sub-grid barrier (64 blocks per bg) ----
        __syncthreads();
        if (tid == 0)
            __hip_atomic_store(&slots[sidx], t + 1, __ATOMIC_RELAXED, __HIP_MEMORY_SCOPE_AGENT);
        if (isagg && tid >= 448) {
            const int sl = tid - 448;
            while (__hip_atomic_load(&slots[sl], __ATOMIC_RELAXED, __HIP_MEMORY_SCOPE_AGENT) <= t)
                __builtin_amdgcn_s_sleep(1);
            if (sl == 0)
                __hip_atomic_store(rel, t + 1, __ATOMIC_RELAXED, __HIP_MEMORY_SCOPE_AGENT);
        }
        if (tid == 0) {
            while (__hip_atomic_load(rel, __ATOMIC_RELAXED, __HIP_MEMORY_SCOPE_AGENT) <= t)
                __builtin_amdgcn_s_sleep(1);
        }
        __syncthreads();
    }
}

// ---------------- final FC ----------------
__global__ __launch_bounds__(256) void k_fc(const float* __restrict__ h1f,
                                            const float* __restrict__ wfc,
                                            const float* __restrict__ bfc,
                                            float* __restrict__ out) {
    int b = blockIdx.x;
    float s0 = 0, s1 = 0, s2 = 0, s3 = 0;
    for (int h = threadIdx.x; h < 512; h += 256) {
        float v = h1f[(size_t)b * 512 + h];
        s0 += v * wfc[h];
        s1 += v * wfc[512 + h];
        s2 += v * wfc[1024 + h];
        s3 += v * wfc[1536 + h];
    }
    #pragma unroll
    for (int off = 32; off; off >>= 1) {
        s0 += __shfl_down(s0, off);
        s1 += __shfl_down(s1, off);
        s2 += __shfl_down(s2, off);
        s3 += __shfl_down(s3, off);
    }
    __shared__ float red[4][4];
    int wid = threadIdx.x >> 6;
    if ((threadIdx.x & 63) == 0) { red[wid][0] = s0; red[wid][1] = s1; red[wid][2] = s2; red[wid][3] = s3; }
    __syncthreads();
    if (threadIdx.x < 4) {
        float s = red[0][threadIdx.x] + red[1][threadIdx.x] + red[2][threadIdx.x] + red[3][threadIdx.x]
                + bfc[threadIdx.x];
        out[b * 4 + threadIdx.x] = s;
    }
}

extern "C" void kernel_launch(void* const* d_in, const int* in_sizes, int n_in,
                              void* d_out, int out_size, void* d_ws, size_t ws_size,
                              hipStream_t stream) {
    const float* x    = (const float*)d_in[0];
    const float* wih0 = (const float*)d_in[1];
    const float* whh0 = (const float*)d_in[2];
    const float* bih0 = (const float*)d_in[3];
    const float* bhh0 = (const float*)d_in[4];
    const float* wih1 = (const float*)d_in[5];
    const float* whh1 = (const float*)d_in[6];
    const float* bih1 = (const float*)d_in[7];
    const float* bhh1 = (const float*)d_in[8];
    const float* wfc  = (const float*)d_in[9];
    const float* bfc  = (const float*)d_in[10];

    if (ws_size < WS_BASE) return;
    const int pre = (ws_size >= WS_PRE) ? 1 : 0;

    char* ws = (char*)d_ws;
    int*   bar   = (int*)(ws + OFF_BAR);
    int*   len   = (int*)(ws + OFF_LEN);
    float* bias0 = (float*)(ws + OFF_BIAS0);
    float* bias1 = (float*)(ws + OFF_BIAS1);
    f16*   W0    = (f16*)(ws + OFF_W0);
    f16*   W1    = (f16*)(ws + OFF_W1);
    f16*   h0a   = (f16*)(ws + OFF_H0A);
    f16*   h0b   = (f16*)(ws + OFF_H0B);
    f16*   h1a   = (f16*)(ws + OFF_H1A);
    f16*   h1b   = (f16*)(ws + OFF_H1B);
    float* h1f   = (float*)(ws + OFF_H1F);
    f16*   X0p   = (f16*)(ws + OFF_X0);

    hipMemsetAsync(ws, 0, 1536, stream);                       // barrier slots/flags + len
    hipMemsetAsync(ws + OFF_H0A, 0, WS_BASE - OFF_H0A, stream); // h state

    k_len<<<dim3(B_, 4), 512, 0, stream>>>(x, len);
    k_wcvt<<<2048, 256, 0, stream>>>(wih0, whh0, bih0, bhh0, W0, bias0);
    k_wcvt<<<2048, 256, 0, stream>>>(wih1, whh1, bih1, bhh1, W1, bias1);
    if (pre) k_xgemm<<<dim3(32, 128, 4), 256, 0, stream>>>(x, W0, bias0, X0p);

    hipFuncSetAttribute((const void*)k_persist, hipFuncAttributeMaxDynamicSharedMemorySize, 147456);
    const f16* X0c = X0p;
    void* kargs[] = {
        (void*)&x, (void*)&W0, (void*)&W1, (void*)&bias0, (void*)&bias1, (void*)&len,
        (void*)&h0a, (void*)&h0b, (void*)&h1a, (void*)&h1b, (void*)&h1f,
        (void*)&X0c, (void*)&pre, (void*)&bar
    };
    hipLaunchCooperativeKernel((const void*)k_persist, dim3(NBLK), dim3(512),
                               kargs, 147456, stream);

    k_fc<<<B_, 256, 0, stream>>>(h1f, wfc, bfc, (float*)d_out);
}

// Round 6
// 7858.925 us; speedup vs baseline: 2.5007x; 1.0042x over previous
//
#include <hip/hip_runtime.h>
#include <hip/hip_fp16.h>

typedef _Float16 f16;
typedef _Float16 f16x8 __attribute__((ext_vector_type(8)));
typedef _Float16 f16x4 __attribute__((ext_vector_type(4)));
typedef float f32x4 __attribute__((ext_vector_type(4)));

#define B_ 128
#define T_ 512
#define I_ 512
#define H_ 512
#define NBLK 128

// ---------------- workspace layout (bytes) ----------------
static constexpr size_t OFF_BAR   = 0;                         // slots[2][64] spaced 16B = 2KB
static constexpr size_t OFF_LEN   = 2048;                      // 128 int
static constexpr size_t OFF_BIAS0 = 4096;                      // 2048 f32
static constexpr size_t OFF_BIAS1 = 12288;                     // 2048 f32
static constexpr size_t OFF_W0    = 32768;                     // 2048x1024 f16, rows u*4+g, [w_ih|w_hh]
static constexpr size_t OFF_W1    = OFF_W0 + 4u*1024u*1024u;
static constexpr size_t OFF_H0A   = OFF_W1 + 4u*1024u*1024u;   // 128x512 f16 each
static constexpr size_t OFF_H0B   = OFF_H0A + 131072;
static constexpr size_t OFF_H1A   = OFF_H0B + 131072;
static constexpr size_t OFF_H1B   = OFF_H1A + 131072;
static constexpr size_t OFF_H1F   = OFF_H1B + 131072;          // 128x512 f32
static constexpr size_t WS_BASE   = OFF_H1F + 262144;
static constexpr size_t OFF_X0    = WS_BASE;                   // f16 [T][B][2048]
static constexpr size_t X0_SZ     = (size_t)T_ * 128 * 2048 * 2;
static constexpr size_t WS_PRE    = OFF_X0 + X0_SZ;

// ---- batched mall-coherent load blobs (bypass L1+L2 via sc0 sc1) ----
__device__ __forceinline__ void ldblob16(const void* p, f16x8* v) {
    asm volatile(
        "global_load_dwordx4 %0, %16, off offset:0 sc0 sc1\n\t"
        "global_load_dwordx4 %1, %16, off offset:64 sc0 sc1\n\t"
        "global_load_dwordx4 %2, %16, off offset:128 sc0 sc1\n\t"
        "global_load_dwordx4 %3, %16, off offset:192 sc0 sc1\n\t"
        "global_load_dwordx4 %4, %16, off offset:256 sc0 sc1\n\t"
        "global_load_dwordx4 %5, %16, off offset:320 sc0 sc1\n\t"
        "global_load_dwordx4 %6, %16, off offset:384 sc0 sc1\n\t"
        "global_load_dwordx4 %7, %16, off offset:448 sc0 sc1\n\t"
        "global_load_dwordx4 %8, %16, off offset:512 sc0 sc1\n\t"
        "global_load_dwordx4 %9, %16, off offset:576 sc0 sc1\n\t"
        "global_load_dwordx4 %10, %16, off offset:640 sc0 sc1\n\t"
        "global_load_dwordx4 %11, %16, off offset:704 sc0 sc1\n\t"
        "global_load_dwordx4 %12, %16, off offset:768 sc0 sc1\n\t"
        "global_load_dwordx4 %13, %16, off offset:832 sc0 sc1\n\t"
        "global_load_dwordx4 %14, %16, off offset:896 sc0 sc1\n\t"
        "global_load_dwordx4 %15, %16, off offset:960 sc0 sc1"
        : "=&v"(v[0]), "=&v"(v[1]), "=&v"(v[2]), "=&v"(v[3]),
          "=&v"(v[4]), "=&v"(v[5]), "=&v"(v[6]), "=&v"(v[7]),
          "=&v"(v[8]), "=&v"(v[9]), "=&v"(v[10]), "=&v"(v[11]),
          "=&v"(v[12]), "=&v"(v[13]), "=&v"(v[14]), "=&v"(v[15])
        : "v"(p) : "memory");
}
__device__ __forceinline__ void ldblob8(const void* p, f16x8* v) {
    asm volatile(
        "global_load_dwordx4 %0, %8, off offset:0 sc0 sc1\n\t"
        "global_load_dwordx4 %1, %8, off offset:64 sc0 sc1\n\t"
        "global_load_dwordx4 %2, %8, off offset:128 sc0 sc1\n\t"
        "global_load_dwordx4 %3, %8, off offset:192 sc0 sc1\n\t"
        "global_load_dwordx4 %4, %8, off offset:256 sc0 sc1\n\t"
        "global_load_dwordx4 %5, %8, off offset:320 sc0 sc1\n\t"
        "global_load_dwordx4 %6, %8, off offset:384 sc0 sc1\n\t"
        "global_load_dwordx4 %7, %8, off offset:448 sc0 sc1"
        : "=&v"(v[0]), "=&v"(v[1]), "=&v"(v[2]), "=&v"(v[3]),
          "=&v"(v[4]), "=&v"(v[5]), "=&v"(v[6]), "=&v"(v[7])
        : "v"(p) : "memory");
}
__device__ __forceinline__ void waitvm0() {
    asm volatile("s_waitcnt vmcnt(0)" ::: "memory");
    __builtin_amdgcn_sched_barrier(0);
}

// ---------------- lengths: count rows with sum != 0 ----------------
__global__ __launch_bounds__(512) void k_len(const float* __restrict__ x, int* __restrict__ len) {
    int b = blockIdx.x, q = blockIdx.y;
    int rl = threadIdx.x >> 2, part = threadIdx.x & 3;
    const float4* p = (const float4*)(x + ((size_t)b * T_ + q * 128 + rl) * I_ + part * 128);
    float s = 0.f;
    #pragma unroll
    for (int i = 0; i < 32; ++i) { float4 v = p[i]; s += v.x + v.y + v.z + v.w; }
    s += __shfl_xor(s, 1);
    s += __shfl_xor(s, 2);
    int cnt = __syncthreads_count(part == 0 && s != 0.0f);
    if (threadIdx.x == 0) atomicAdd(&len[b], cnt);
}

// ---------------- weight convert: rows u*4+gate, concat [w_ih|w_hh], f32->f16 ----------------
__global__ __launch_bounds__(256) void k_wcvt(const float* __restrict__ wih, const float* __restrict__ whh,
                                              const float* __restrict__ bih, const float* __restrict__ bhh,
                                              f16* __restrict__ W, float* __restrict__ bias) {
    int r = blockIdx.x;          // reordered row = u*4+g
    int h = r >> 2, g = r & 3;
    int src = g * 512 + h;
    const float* a = wih + (size_t)src * 512;
    const float* bsrc = whh + (size_t)src * 512;
    f16* dst = W + (size_t)r * 1024;
    #pragma unroll
    for (int j = 0; j < 2; ++j) {
        int k = threadIdx.x + j * 256;
        dst[k]       = (f16)a[k];
        dst[k + 512] = (f16)bsrc[k];
    }
    if (threadIdx.x == 0) bias[r] = bih[src] + bhh[src];
}

// ---------------- X0 precompute: X0[t][b][:] = x[b][t][:] @ w_ih0^T + b0 ----------------
// X0 is written once / read once -> non-temporal (do NOT pollute the 256MB MALL;
// h-state exchange in k_persist must stay L3-resident).
__global__ __launch_bounds__(256) void k_xgemm(const float* __restrict__ x, const f16* __restrict__ W0,
                                               const float* __restrict__ bias0, f16* __restrict__ X0) {
    __shared__ char lds[65536];
    const int cg = blockIdx.x, b = blockIdx.y, tc = blockIdx.z;
    const int tid = threadIdx.x;
    const int wv = tid >> 6, lane = tid & 63;
    const int l16 = lane & 15, l4 = lane >> 4;
    const int nf = wv;
    {
        const int r = tid >> 2, e = tid & 3;
        const f16* src = W0 + (size_t)(cg * 64 + r) * 1024 + e * 128;
        char* rowp = lds + r * 1024;
        const int sw = (r & 7) << 4;
        #pragma unroll
        for (int j = 0; j < 16; ++j) {
            const int byte = e * 256 + j * 16;
            *(f16x8*)(rowp + (byte ^ sw)) = *(const f16x8*)(src + j * 8);
        }
    }
    __syncthreads();
    const int row_l = nf * 16 + l16;
    const char* Wrow = lds + row_l * 1024;
    const int wsw = (row_l & 7) << 4;
    const int koff = l4 * 8;
    f32x4 acc[8] = {};
    #pragma unroll 4
    for (int ks = 0; ks < 16; ++ks) {
        f16x8 aw = *(const f16x8*)(Wrow + (((ks * 32 + koff) * 2) ^ wsw));
        #pragma unroll
        for (int mf = 0; mf < 8; ++mf) {
            const int tt = tc * 128 + mf * 16 + l16;
            const float* xp = x + ((size_t)b * 512 + tt) * 512 + ks * 32 + koff;
            const float4 p0 = *(const float4*)xp;
            const float4 p1 = *(const float4*)(xp + 4);
            f16x8 v = { (f16)p0.x,(f16)p0.y,(f16)p0.z,(f16)p0.w,
                        (f16)p1.x,(f16)p1.y,(f16)p1.z,(f16)p1.w };
            acc[mf] = __builtin_amdgcn_mfma_f32_16x16x32_f16(aw, v, acc[mf], 0, 0, 0);
        }
    }
    const float4 b4 = *(const float4*)(bias0 + cg * 64 + nf * 16 + l4 * 4);
    const float bb[4] = { b4.x, b4.y, b4.z, b4.w };
    #pragma unroll
    for (int mf = 0; mf < 8; ++mf) {
        const int tt = tc * 128 + mf * 16 + l16;
        f16x4 v;
        #pragma unroll
        for (int g = 0; g < 4; ++g) v[g] = (f16)(acc[mf][g] + bb[g]);
        __builtin_nontemporal_store(v, (f16x4*)(X0 + ((size_t)tt * 128 + b) * 2048 + cg * 64 + nf * 16 + l4 * 4));
    }
}

// ---------------- persistent kernel ----------------
// 128 blocks x 512 thr. Block = layer (bid>>6) x bg (bid>>5)&1 x cg (bid&31).
// Waves: kh = wv&1 (K-half/operand), mfg = (wv>>1)&1 (32 batches), nfg = wv>>2 (8 units).
// Weights in LDS in fragment-major order (conflict-free ds_read_b128, imm offsets).
// h loads: one asm blob of mall-coherent dwordx4 per wave (single round trip).
// X0: non-temporal loads (streamed, no MALL allocation).
// Barrier: per-block arrival slot + direct poll of all 64 slots by wave 0. No fences.
__global__ __launch_bounds__(512) void k_persist(
    const float* __restrict__ x,
    const f16* __restrict__ W0, const f16* __restrict__ W1,
    const float* __restrict__ bias0, const float* __restrict__ bias1,
    const int* __restrict__ len,
    f16* __restrict__ h0a, f16* __restrict__ h0b,
    f16* __restrict__ h1a, f16* __restrict__ h1b,
    float* __restrict__ h1f,
    const f16* __restrict__ X0, int pre, int* bar)
{
    extern __shared__ char lds[];          // 128K weights (frag-major) + 16K reduce buf
    char* Rbuf = lds + 131072;
    const int tid = threadIdx.x;
    const int bid = blockIdx.x;
    const int layer = bid >> 6;
    const int bg = (bid >> 5) & 1;
    const int cg = bid & 31;
    const int wv = tid >> 6, lane = tid & 63;
    const int kh = wv & 1, mfg = (wv >> 1) & 1, nfg = wv >> 2;
    const int l16 = lane & 15, l4 = lane >> 4;

    int* slots = bar + bg * 256;           // 64 slots spaced 4 ints (16B)
    const int sidx = layer * 32 + cg;

    // ---- stage weights into LDS, fragment-major: frag f = (k>>9)*64 + ((k>>5)&15)*4 + (r>>4)
    //      byte = f*1024 + (((k>>3)&3)*16 + (r&15))*16 + (k&7)*2
    {
        const f16* Wsrc = (layer ? W1 : W0) + (size_t)(cg * 64) * 1024;
        #pragma unroll
        for (int j = 0; j < 16; ++j) {
            int cid = j * 512 + tid;               // 8192 16B-chunks: r = cid>>7, kc = cid&127
            int r = cid >> 7, kc = cid & 127;
            f16x8 w = *(const f16x8*)(Wsrc + (size_t)r * 1024 + kc * 8);
            int f = (kc >> 6) * 64 + ((kc >> 2) & 15) * 4 + (r >> 4);
            *(f16x8*)(lds + f * 1024 + ((kc & 3) * 16 + (r & 15)) * 16) = w;
        }
    }

    const int bbA = bg * 64 + mfg * 32 + l16;      // batches (two m-frags per wave)
    const int bbB = bbA + 16;
    const int lbA = len[bbA], lbB = len[bbB];
    float4 bias4[2];
    #pragma unroll
    for (int ni = 0; ni < 2; ++ni) {
        const int u = cg * 16 + (nfg * 2 + ni) * 4 + l4;
        if (layer) bias4[ni] = *(const float4*)(bias1 + u * 4);
        else if (!pre) bias4[ni] = *(const float4*)(bias0 + u * 4);
        else bias4[ni] = make_float4(0.f, 0.f, 0.f, 0.f);
    }
    float c_s[2][2] = {};
    f16 h_s[2][2] = {};

    __syncthreads();

    for (int t = 0; t <= T_; ++t) {
        const int step = layer ? (t - 1) : t;
        const bool active = (step >= 0) && (step < T_);
        if (active) {
            f32x4 acc[2][2] = {};
            f16x8 hvA[16], hvB[16];
            f16x4 x0v[2][2];

            if (layer == 0) {
                const f16* hprev = (t & 1) ? h0a : h0b;              // h0(t-1)
                if (pre) {
                    if (kh == 0) {                                    // X0 prefetch (non-temporal)
                        #pragma unroll
                        for (int mi = 0; mi < 2; ++mi)
                            #pragma unroll
                            for (int ni = 0; ni < 2; ++ni)
                                x0v[mi][ni] = __builtin_nontemporal_load(
                                    (const f16x4*)(X0 + ((size_t)t * 128 + (mi ? bbB : bbA)) * 2048
                                                   + (cg * 16 + (nfg * 2 + ni) * 4 + l4) * 4));
                    }
                    const char* pA = (const char*)hprev + bbA * 1024 + kh * 512 + l4 * 16;
                    const char* pB = (const char*)hprev + bbB * 1024 + kh * 512 + l4 * 16;
                    ldblob8(pA, hvA);
                    ldblob8(pB, hvB);
                    waitvm0();
                    const char* wb = lds + (64 + kh * 32 + nfg * 2) * 1024 + lane * 16;
                    #pragma unroll
                    for (int ks = 0; ks < 8; ++ks) {
                        f16x8 w0 = *(const f16x8*)(wb + (ks * 4 + 0) * 1024);
                        f16x8 w1 = *(const f16x8*)(wb + (ks * 4 + 1) * 1024);
                        acc[0][0] = __builtin_amdgcn_mfma_f32_16x16x32_f16(w0, hvA[ks], acc[0][0], 0, 0, 0);
                        acc[0][1] = __builtin_amdgcn_mfma_f32_16x16x32_f16(w1, hvA[ks], acc[0][1], 0, 0, 0);
                        acc[1][0] = __builtin_amdgcn_mfma_f32_16x16x32_f16(w0, hvB[ks], acc[1][0], 0, 0, 0);
                        acc[1][1] = __builtin_amdgcn_mfma_f32_16x16x32_f16(w1, hvB[ks], acc[1][1], 0, 0, 0);
                    }
                } else {
                    if (kh == 0) {                                    // ih on x (f32->f16), K=512
                        const float* xp0 = x + ((size_t)bbA * 512 + t) * 512 + l4 * 8;
                        const float* xp1 = x + ((size_t)bbB * 512 + t) * 512 + l4 * 8;
                        const char* wb = lds + (nfg * 2) * 1024 + lane * 16;
                        #pragma unroll
                        for (int ks = 0; ks < 16; ++ks) {
                            const float4 p0 = *(const float4*)(xp0 + ks * 32);
                            const float4 p1 = *(const float4*)(xp0 + ks * 32 + 4);
                            const float4 p2 = *(const float4*)(xp1 + ks * 32);
                            const float4 p3 = *(const float4*)(xp1 + ks * 32 + 4);
                            f16x8 vA = { (f16)p0.x,(f16)p0.y,(f16)p0.z,(f16)p0.w,
                                         (f16)p1.x,(f16)p1.y,(f16)p1.z,(f16)p1.w };
                            f16x8 vB = { (f16)p2.x,(f16)p2.y,(f16)p2.z,(f16)p2.w,
                                         (f16)p3.x,(f16)p3.y,(f16)p3.z,(f16)p3.w };
                            f16x8 w0 = *(const f16x8*)(wb + (ks * 4 + 0) * 1024);
                            f16x8 w1 = *(const f16x8*)(wb + (ks * 4 + 1) * 1024);
                            acc[0][0] = __builtin_amdgcn_mfma_f32_16x16x32_f16(w0, vA, acc[0][0], 0, 0, 0);
                            acc[0][1] = __builtin_amdgcn_mfma_f32_16x16x32_f16(w1, vA, acc[0][1], 0, 0, 0);
                            acc[1][0] = __builtin_amdgcn_mfma_f32_16x16x32_f16(w0, vB, acc[1][0], 0, 0, 0);
                            acc[1][1] = __builtin_amdgcn_mfma_f32_16x16x32_f16(w1, vB, acc[1][1], 0, 0, 0);
                        }
                    } else {                                          // hh on h0(t-1), K=512
                        const char* pA = (const char*)hprev + bbA * 1024 + l4 * 16;
                        const char* pB = (const char*)hprev + bbB * 1024 + l4 * 16;
                        ldblob16(pA, hvA);
                        ldblob16(pB, hvB);
                        waitvm0();
                        const char* wb = lds + (64 + nfg * 2) * 1024 + lane * 16;
                        #pragma unroll
                        for (int ks = 0; ks < 16; ++ks) {
                            f16x8 w0 = *(const f16x8*)(wb + (ks * 4 + 0) * 1024);
                            f16x8 w1 = *(const f16x8*)(wb + (ks * 4 + 1) * 1024);
                            acc[0][0] = __builtin_amdgcn_mfma_f32_16x16x32_f16(w0, hvA[ks], acc[0][0], 0, 0, 0);
                            acc[0][1] = __builtin_amdgcn_mfma_f32_16x16x32_f16(w1, hvA[ks], acc[0][1], 0, 0, 0);
                            acc[1][0] = __builtin_amdgcn_mfma_f32_16x16x32_f16(w0, hvB[ks], acc[1][0], 0, 0, 0);
                            acc[1][1] = __builtin_amdgcn_mfma_f32_16x16x32_f16(w1, hvB[ks], acc[1][1], 0, 0, 0);
                        }
                    }
                }
            } else {
                const int s = step;
                const f16* hsrc = (kh == 0) ? ((s & 1) ? h0b : h0a)   // ih: h0(s)
                                            : ((s & 1) ? h1a : h1b);  // hh: h1(s-1)
                const char* pA = (const char*)hsrc + bbA * 1024 + l4 * 16;
                const char* pB = (const char*)hsrc + bbB * 1024 + l4 * 16;
                ldblob16(pA, hvA);
                ldblob16(pB, hvB);
                waitvm0();
                const char* wb = lds + (kh * 64 + nfg * 2) * 1024 + lane * 16;
                #pragma unroll
                for (int ks = 0; ks < 16; ++ks) {
                    f16x8 w0 = *(const f16x8*)(wb + (ks * 4 + 0) * 1024);
                    f16x8 w1 = *(const f16x8*)(wb + (ks * 4 + 1) * 1024);
                    acc[0][0] = __builtin_amdgcn_mfma_f32_16x16x32_f16(w0, hvA[ks], acc[0][0], 0, 0, 0);
                    acc[0][1] = __builtin_amdgcn_mfma_f32_16x16x32_f16(w1, hvA[ks], acc[0][1], 0, 0, 0);
                    acc[1][0] = __builtin_amdgcn_mfma_f32_16x16x32_f16(w0, hvB[ks], acc[1][0], 0, 0, 0);
                    acc[1][1] = __builtin_amdgcn_mfma_f32_16x16x32_f16(w1, hvB[ks], acc[1][1], 0, 0, 0);
                }
            }

            // ---- kh pair-reduce through LDS ----
            if (kh == 1) {
                const int g = wv >> 1;
                #pragma unroll
                for (int mi = 0; mi < 2; ++mi)
                    #pragma unroll
                    for (int ni = 0; ni < 2; ++ni)
                        *(f32x4*)(Rbuf + (((g * 4 + mi * 2 + ni) * 64) + lane) * 16) = acc[mi][ni];
            }
            __syncthreads();
            if (kh == 0) {
                const int g = wv >> 1;
                #pragma unroll
                for (int mi = 0; mi < 2; ++mi)
                    #pragma unroll
                    for (int ni = 0; ni < 2; ++ni)
                        acc[mi][ni] += *(const f32x4*)(Rbuf + (((g * 4 + mi * 2 + ni) * 64) + lane) * 16);

                f16* hw = (layer == 0) ? ((t & 1) ? h0b : h0a)        // h0(t)
                                       : ((step & 1) ? h1b : h1a);    // h1(s)
                #pragma unroll
                for (int mi = 0; mi < 2; ++mi) {
                    const int bb = mi ? bbB : bbA;
                    const int lbv = mi ? lbB : lbA;
                    const bool msk = step < lbv;
                    #pragma unroll
                    for (int ni = 0; ni < 2; ++ni) {
                        const int u = cg * 16 + (nfg * 2 + ni) * 4 + l4;
                        float g0, g1, g2, g3;
                        if (layer == 0 && pre) {
                            g0 = (float)x0v[mi][ni][0]; g1 = (float)x0v[mi][ni][1];
                            g2 = (float)x0v[mi][ni][2]; g3 = (float)x0v[mi][ni][3];
                        } else {
                            g0 = bias4[ni].x; g1 = bias4[ni].y; g2 = bias4[ni].z; g3 = bias4[ni].w;
                        }
                        const float gi = acc[mi][ni][0] + g0, gf = acc[mi][ni][1] + g1;
                        const float gg = acc[mi][ni][2] + g2, go = acc[mi][ni][3] + g3;
                        const float cn = (1.f / (1.f + expf(-gf))) * c_s[mi][ni]
                                       + (1.f / (1.f + expf(-gi))) * tanhf(gg);
                        const float hn = (1.f / (1.f + expf(-go))) * tanhf(cn);
                        if (msk) { c_s[mi][ni] = cn; h_s[mi][ni] = (f16)hn; }
                        union { f16 h; uint16_t u16; } cv; cv.h = h_s[mi][ni];
                        const int pb = __shfl_xor((int)cv.u16, 16);
                        if ((l4 & 1) == 0) {
                            const uint32_t w = (uint32_t)cv.u16 | ((uint32_t)(uint16_t)pb << 16);
                            __hip_atomic_store((uint32_t*)(hw + (size_t)bb * 512 + u), w,
                                               __ATOMIC_RELAXED, __HIP_MEMORY_SCOPE_AGENT);
                        }
                        if (layer == 1 && step == lbv - 1) h1f[(size_t)bb * 512 + u] = hn;
                    }
                }
            }
        }

        // ---- direct-poll sub-grid barrier (64 blocks per bg) ----
        __syncthreads();                  // all waves' stores drained (vmcnt 0 per wave)
        if (tid == 0)
            __hip_atomic_store(&slots[sidx * 4], t + 1, __ATOMIC_RELAXED, __HIP_MEMORY_SCOPE_AGENT);
        if (tid < 64) {                   // wave 0: lane i polls slot i
            while (__any(__hip_atomic_load(&slots[tid * 4], __ATOMIC_RELAXED,
                                           __HIP_MEMORY_SCOPE_AGENT) <= t))
                __builtin_amdgcn_s_sleep(1);
        }
        __syncthreads();
    }
}

// ---------------- final FC ----------------
__global__ __launch_bounds__(256) void k_fc(const float* __restrict__ h1f,
                                            const float* __restrict__ wfc,
                                            const float* __restrict__ bfc,
                                            float* __restrict__ out) {
    int b = blockIdx.x;
    float s0 = 0, s1 = 0, s2 = 0, s3 = 0;
    for (int h = threadIdx.x; h < 512; h += 256) {
        float v = h1f[(size_t)b * 512 + h];
        s0 += v * wfc[h];
        s1 += v * wfc[512 + h];
        s2 += v * wfc[1024 + h];
        s3 += v * wfc[1536 + h];
    }
    #pragma unroll
    for (int off = 32; off; off >>= 1) {
        s0 += __shfl_down(s0, off);
        s1 += __shfl_down(s1, off);
        s2 += __shfl_down(s2, off);
        s3 += __shfl_down(s3, off);
    }
    __shared__ float red[4][4];
    int wid = threadIdx.x >> 6;
    if ((threadIdx.x & 63) == 0) { red[wid][0] = s0; red[wid][1] = s1; red[wid][2] = s2; red[wid][3] = s3; }
    __syncthreads();
    if (threadIdx.x < 4) {
        float s = red[0][threadIdx.x] + red[1][threadIdx.x] + red[2][threadIdx.x] + red[3][threadIdx.x]
                + bfc[threadIdx.x];
        out[b * 4 + threadIdx.x] = s;
    }
}

extern "C" void kernel_launch(void* const* d_in, const int* in_sizes, int n_in,
                              void* d_out, int out_size, void* d_ws, size_t ws_size,
                              hipStream_t stream) {
    const float* x    = (const float*)d_in[0];
    const float* wih0 = (const float*)d_in[1];
    const float* whh0 = (const float*)d_in[2];
    const float* bih0 = (const float*)d_in[3];
    const float* bhh0 = (const float*)d_in[4];
    const float* wih1 = (const float*)d_in[5];
    const float* whh1 = (const float*)d_in[6];
    const float* bih1 = (const float*)d_in[7];
    const float* bhh1 = (const float*)d_in[8];
    const float* wfc  = (const float*)d_in[9];
    const float* bfc  = (const float*)d_in[10];

    if (ws_size < WS_BASE) return;
    const int pre = (ws_size >= WS_PRE) ? 1 : 0;

    char* ws = (char*)d_ws;
    int*   bar   = (int*)(ws + OFF_BAR);
    int*   len   = (int*)(ws + OFF_LEN);
    float* bias0 = (float*)(ws + OFF_BIAS0);
    float* bias1 = (float*)(ws + OFF_BIAS1);
    f16*   W0    = (f16*)(ws + OFF_W0);
    f16*   W1    = (f16*)(ws + OFF_W1);
    f16*   h0a   = (f16*)(ws + OFF_H0A);
    f16*   h0b   = (f16*)(ws + OFF_H0B);
    f16*   h1a   = (f16*)(ws + OFF_H1A);
    f16*   h1b   = (f16*)(ws + OFF_H1B);
    float* h1f   = (float*)(ws + OFF_H1F);
    f16*   X0p   = (f16*)(ws + OFF_X0);

    hipMemsetAsync(ws, 0, 4096, stream);                        // barrier slots + len
    hipMemsetAsync(ws + OFF_H0A, 0, WS_BASE - OFF_H0A, stream); // h state

    k_len<<<dim3(B_, 4), 512, 0, stream>>>(x, len);
    k_wcvt<<<2048, 256, 0, stream>>>(wih0, whh0, bih0, bhh0, W0, bias0);
    k_wcvt<<<2048, 256, 0, stream>>>(wih1, whh1, bih1, bhh1, W1, bias1);
    if (pre) k_xgemm<<<dim3(32, 128, 4), 256, 0, stream>>>(x, W0, bias0, X0p);

    hipFuncSetAttribute((const void*)k_persist, hipFuncAttributeMaxDynamicSharedMemorySize, 147456);
    const f16* X0c = X0p;
    void* kargs[] = {
        (void*)&x, (void*)&W0, (void*)&W1, (void*)&bias0, (void*)&bias1, (void*)&len,
        (void*)&h0a, (void*)&h0b, (void*)&h1a, (void*)&h1b, (void*)&h1f,
        (void*)&X0c, (void*)&pre, (void*)&bar
    };
    hipLaunchCooperativeKernel((const void*)k_persist, dim3(NBLK), dim3(512),
                               kargs, 147456, stream);

    k_fc<<<B_, 256, 0, stream>>>(h1f, wfc, bfc, (float*)d_out);
}

// Round 7
// 6203.399 us; speedup vs baseline: 3.1680x; 1.2669x over previous
//
#include <hip/hip_runtime.h>
#include <hip/hip_fp16.h>

typedef _Float16 f16;
typedef _Float16 f16x8 __attribute__((ext_vector_type(8)));
typedef _Float16 f16x4 __attribute__((ext_vector_type(4)));
typedef float f32x4 __attribute__((ext_vector_type(4)));

#define B_ 128
#define T_ 512
#define I_ 512
#define H_ 512
#define NBLK 128

// ---------------- workspace layout (bytes) ----------------
static constexpr size_t OFF_BAR   = 0;                         // slots[2][64] spaced 16B = 2KB
static constexpr size_t OFF_LEN   = 2048;                      // 128 int
static constexpr size_t OFF_BIAS0 = 4096;                      // 2048 f32
static constexpr size_t OFF_BIAS1 = 12288;                     // 2048 f32
static constexpr size_t OFF_W0    = 32768;                     // 2048x1024 f16, rows u*4+g, [w_ih|w_hh]
static constexpr size_t OFF_W1    = OFF_W0 + 4u*1024u*1024u;
static constexpr size_t OFF_H0A   = OFF_W1 + 4u*1024u*1024u;   // 128x512 f16 each
static constexpr size_t OFF_H0B   = OFF_H0A + 131072;
static constexpr size_t OFF_H1A   = OFF_H0B + 131072;
static constexpr size_t OFF_H1B   = OFF_H1A + 131072;
static constexpr size_t OFF_H1F   = OFF_H1B + 131072;          // 128x512 f32
static constexpr size_t WS_BASE   = OFF_H1F + 262144;
static constexpr size_t OFF_X0    = WS_BASE;                   // f16 [T][B][2048]
static constexpr size_t X0_SZ     = (size_t)T_ * 128 * 2048 * 2;
static constexpr size_t WS_PRE    = OFF_X0 + X0_SZ;

// ---- batched mall-coherent load blobs (bypass L1+L2 via sc0 sc1) ----
__device__ __forceinline__ void ldblob16(const void* p, f16x8* v) {
    asm volatile(
        "global_load_dwordx4 %0, %16, off offset:0 sc0 sc1\n\t"
        "global_load_dwordx4 %1, %16, off offset:64 sc0 sc1\n\t"
        "global_load_dwordx4 %2, %16, off offset:128 sc0 sc1\n\t"
        "global_load_dwordx4 %3, %16, off offset:192 sc0 sc1\n\t"
        "global_load_dwordx4 %4, %16, off offset:256 sc0 sc1\n\t"
        "global_load_dwordx4 %5, %16, off offset:320 sc0 sc1\n\t"
        "global_load_dwordx4 %6, %16, off offset:384 sc0 sc1\n\t"
        "global_load_dwordx4 %7, %16, off offset:448 sc0 sc1\n\t"
        "global_load_dwordx4 %8, %16, off offset:512 sc0 sc1\n\t"
        "global_load_dwordx4 %9, %16, off offset:576 sc0 sc1\n\t"
        "global_load_dwordx4 %10, %16, off offset:640 sc0 sc1\n\t"
        "global_load_dwordx4 %11, %16, off offset:704 sc0 sc1\n\t"
        "global_load_dwordx4 %12, %16, off offset:768 sc0 sc1\n\t"
        "global_load_dwordx4 %13, %16, off offset:832 sc0 sc1\n\t"
        "global_load_dwordx4 %14, %16, off offset:896 sc0 sc1\n\t"
        "global_load_dwordx4 %15, %16, off offset:960 sc0 sc1"
        : "=&v"(v[0]), "=&v"(v[1]), "=&v"(v[2]), "=&v"(v[3]),
          "=&v"(v[4]), "=&v"(v[5]), "=&v"(v[6]), "=&v"(v[7]),
          "=&v"(v[8]), "=&v"(v[9]), "=&v"(v[10]), "=&v"(v[11]),
          "=&v"(v[12]), "=&v"(v[13]), "=&v"(v[14]), "=&v"(v[15])
        : "v"(p) : "memory");
}
__device__ __forceinline__ void ldblob8(const void* p, f16x8* v) {
    asm volatile(
        "global_load_dwordx4 %0, %8, off offset:0 sc0 sc1\n\t"
        "global_load_dwordx4 %1, %8, off offset:64 sc0 sc1\n\t"
        "global_load_dwordx4 %2, %8, off offset:128 sc0 sc1\n\t"
        "global_load_dwordx4 %3, %8, off offset:192 sc0 sc1\n\t"
        "global_load_dwordx4 %4, %8, off offset:256 sc0 sc1\n\t"
        "global_load_dwordx4 %5, %8, off offset:320 sc0 sc1\n\t"
        "global_load_dwordx4 %6, %8, off offset:384 sc0 sc1\n\t"
        "global_load_dwordx4 %7, %8, off offset:448 sc0 sc1"
        : "=&v"(v[0]), "=&v"(v[1]), "=&v"(v[2]), "=&v"(v[3]),
          "=&v"(v[4]), "=&v"(v[5]), "=&v"(v[6]), "=&v"(v[7])
        : "v"(p) : "memory");
}
__device__ __forceinline__ void waitvm0() {
    asm volatile("s_waitcnt vmcnt(0)" ::: "memory");
    __builtin_amdgcn_sched_barrier(0);
}
// 16B write-through store (visible at mall without fences)
__device__ __forceinline__ void stwt16(void* p, f16x8 v) {
    asm volatile("global_store_dwordx4 %0, %1, off sc0 sc1" :: "v"(p), "v"(v) : "memory");
}

// ---------------- lengths: count rows with sum != 0 ----------------
__global__ __launch_bounds__(512) void k_len(const float* __restrict__ x, int* __restrict__ len) {
    int b = blockIdx.x, q = blockIdx.y;
    int rl = threadIdx.x >> 2, part = threadIdx.x & 3;
    const float4* p = (const float4*)(x + ((size_t)b * T_ + q * 128 + rl) * I_ + part * 128);
    float s = 0.f;
    #pragma unroll
    for (int i = 0; i < 32; ++i) { float4 v = p[i]; s += v.x + v.y + v.z + v.w; }
    s += __shfl_xor(s, 1);
    s += __shfl_xor(s, 2);
    int cnt = __syncthreads_count(part == 0 && s != 0.0f);
    if (threadIdx.x == 0) atomicAdd(&len[b], cnt);
}

// ---------------- weight convert: rows u*4+gate, concat [w_ih|w_hh], f32->f16 ----------------
__global__ __launch_bounds__(256) void k_wcvt(const float* __restrict__ wih, const float* __restrict__ whh,
                                              const float* __restrict__ bih, const float* __restrict__ bhh,
                                              f16* __restrict__ W, float* __restrict__ bias) {
    int r = blockIdx.x;          // reordered row = u*4+g
    int h = r >> 2, g = r & 3;
    int src = g * 512 + h;
    const float* a = wih + (size_t)src * 512;
    const float* bsrc = whh + (size_t)src * 512;
    f16* dst = W + (size_t)r * 1024;
    #pragma unroll
    for (int j = 0; j < 2; ++j) {
        int k = threadIdx.x + j * 256;
        dst[k]       = (f16)a[k];
        dst[k + 512] = (f16)bsrc[k];
    }
    if (threadIdx.x == 0) bias[r] = bih[src] + bhh[src];
}

// ---------------- X0 precompute: X0[t][b][:] = x[b][t][:] @ w_ih0^T + b0 ----------------
__global__ __launch_bounds__(256) void k_xgemm(const float* __restrict__ x, const f16* __restrict__ W0,
                                               const float* __restrict__ bias0, f16* __restrict__ X0) {
    __shared__ char lds[65536];
    const int cg = blockIdx.x, b = blockIdx.y, tc = blockIdx.z;
    const int tid = threadIdx.x;
    const int wv = tid >> 6, lane = tid & 63;
    const int l16 = lane & 15, l4 = lane >> 4;
    const int nf = wv;
    {
        const int r = tid >> 2, e = tid & 3;
        const f16* src = W0 + (size_t)(cg * 64 + r) * 1024 + e * 128;
        char* rowp = lds + r * 1024;
        const int sw = (r & 7) << 4;
        #pragma unroll
        for (int j = 0; j < 16; ++j) {
            const int byte = e * 256 + j * 16;
            *(f16x8*)(rowp + (byte ^ sw)) = *(const f16x8*)(src + j * 8);
        }
    }
    __syncthreads();
    const int row_l = nf * 16 + l16;
    const char* Wrow = lds + row_l * 1024;
    const int wsw = (row_l & 7) << 4;
    const int koff = l4 * 8;
    f32x4 acc[8] = {};
    #pragma unroll 4
    for (int ks = 0; ks < 16; ++ks) {
        f16x8 aw = *(const f16x8*)(Wrow + (((ks * 32 + koff) * 2) ^ wsw));
        #pragma unroll
        for (int mf = 0; mf < 8; ++mf) {
            const int tt = tc * 128 + mf * 16 + l16;
            const float* xp = x + ((size_t)b * 512 + tt) * 512 + ks * 32 + koff;
            const float4 p0 = *(const float4*)xp;
            const float4 p1 = *(const float4*)(xp + 4);
            f16x8 v = { (f16)p0.x,(f16)p0.y,(f16)p0.z,(f16)p0.w,
                        (f16)p1.x,(f16)p1.y,(f16)p1.z,(f16)p1.w };
            acc[mf] = __builtin_amdgcn_mfma_f32_16x16x32_f16(aw, v, acc[mf], 0, 0, 0);
        }
    }
    const float4 b4 = *(const float4*)(bias0 + cg * 64 + nf * 16 + l4 * 4);
    const float bb[4] = { b4.x, b4.y, b4.z, b4.w };
    #pragma unroll
    for (int mf = 0; mf < 8; ++mf) {
        const int tt = tc * 128 + mf * 16 + l16;
        f16x4 v;
        #pragma unroll
        for (int g = 0; g < 4; ++g) v[g] = (f16)(acc[mf][g] + bb[g]);
        __builtin_nontemporal_store(v, (f16x4*)(X0 + ((size_t)tt * 128 + b) * 2048 + cg * 64 + nf * 16 + l4 * 4));
    }
}

// ---------------- persistent kernel ----------------
// 128 blocks x 512 thr, launch_bounds(512,2) -> VGPR cap 256 (NO spill of load blobs).
// Block = layer (bid>>6) x bg (bid>>5)&1 x cg (bid&31).
// Waves: kh = wv&1 (K-half/operand), mfg = wv>>1 (16-batch group). Each wave owns all 4
// n-frags -> 1x h-load redundancy, 64 live h-VGPRs. Rbuf pair-reduce over kh.
// h stores: repacked through LDS, 16B write-through coalesced stores.
__global__ __launch_bounds__(512, 2) void k_persist(
    const float* __restrict__ x,
    const f16* __restrict__ W0, const f16* __restrict__ W1,
    const float* __restrict__ bias0, const float* __restrict__ bias1,
    const int* __restrict__ len,
    f16* __restrict__ h0a, f16* __restrict__ h0b,
    f16* __restrict__ h1a, f16* __restrict__ h1b,
    float* __restrict__ h1f,
    const f16* __restrict__ X0, int pre, int* bar)
{
    extern __shared__ char lds[];          // 128K weights (frag-major) + 16K Rbuf + 2K hstage
    char* Rbuf   = lds + 131072;
    char* hstage = lds + 147456;
    const int tid = threadIdx.x;
    const int bid = blockIdx.x;
    const int layer = bid >> 6;
    const int bg = (bid >> 5) & 1;
    const int cg = bid & 31;
    const int wv = tid >> 6, lane = tid & 63;
    const int kh = wv & 1, mfg = wv >> 1;
    const int l16 = lane & 15, l4 = lane >> 4;

    int* slots = bar + bg * 256;           // 64 slots spaced 4 ints (16B)
    const int sidx = layer * 32 + cg;

    // ---- stage weights into LDS, fragment-major: frag f = (k>>9)*64 + ((k>>5)&15)*4 + (r>>4)
    {
        const f16* Wsrc = (layer ? W1 : W0) + (size_t)(cg * 64) * 1024;
        #pragma unroll
        for (int j = 0; j < 16; ++j) {
            int cid = j * 512 + tid;               // 8192 16B-chunks: r = cid>>7, kc = cid&127
            int r = cid >> 7, kc = cid & 127;
            f16x8 w = *(const f16x8*)(Wsrc + (size_t)r * 1024 + kc * 8);
            int f = (kc >> 6) * 64 + ((kc >> 2) & 15) * 4 + (r >> 4);
            *(f16x8*)(lds + f * 1024 + ((kc & 3) * 16 + (r & 15)) * 16) = w;
        }
    }

    const int bb = bg * 64 + mfg * 16 + l16;       // this lane's batch
    const int lb = len[bb];
    float4 bias4[4];
    #pragma unroll
    for (int nf = 0; nf < 4; ++nf) {
        const int u = cg * 16 + nf * 4 + l4;
        if (layer) bias4[nf] = *(const float4*)(bias1 + u * 4);
        else if (!pre) bias4[nf] = *(const float4*)(bias0 + u * 4);
        else bias4[nf] = make_float4(0.f, 0.f, 0.f, 0.f);
    }
    float c_s[4] = {};
    f16 h_s[4] = {};

    __syncthreads();

    for (int t = 0; t <= T_; ++t) {
        const int step = layer ? (t - 1) : t;
        const bool active = (step >= 0) && (step < T_);
        if (active) {
            f32x4 acc[4] = {};
            f16x8 hv[16];
            f16x4 x0v[4];

            if (layer == 0) {
                const f16* hprev = (t & 1) ? h0a : h0b;              // h0(t-1)
                if (pre) {
                    if (kh == 0) {                                    // X0 prefetch (epilogue use)
                        #pragma unroll
                        for (int nf = 0; nf < 4; ++nf)
                            x0v[nf] = __builtin_nontemporal_load(
                                (const f16x4*)(X0 + ((size_t)t * 128 + bb) * 2048
                                               + (cg * 16 + nf * 4 + l4) * 4));
                    }
                    // hh on h0(t-1): K=512, kh halves it (8 ks each)
                    const char* p = (const char*)hprev + bb * 1024 + kh * 512 + l4 * 16;
                    ldblob8(p, hv);
                    waitvm0();
                    const char* wb = lds + (size_t)(64 + kh * 32) * 1024 + lane * 16;
                    #pragma unroll
                    for (int ks = 0; ks < 8; ++ks) {
                        #pragma unroll
                        for (int nf = 0; nf < 4; ++nf) {
                            f16x8 w = *(const f16x8*)(wb + (ks * 4 + nf) * 1024);
                            acc[nf] = __builtin_amdgcn_mfma_f32_16x16x32_f16(w, hv[ks], acc[nf], 0, 0, 0);
                        }
                    }
                } else {
                    if (kh == 0) {                                    // ih on x (f32->f16), K=512
                        const float* xp = x + ((size_t)bb * 512 + t) * 512 + l4 * 8;
                        const char* wb = lds + lane * 16;
                        #pragma unroll
                        for (int ks = 0; ks < 16; ++ks) {
                            const float4 p0 = *(const float4*)(xp + ks * 32);
                            const float4 p1 = *(const float4*)(xp + ks * 32 + 4);
                            f16x8 v = { (f16)p0.x,(f16)p0.y,(f16)p0.z,(f16)p0.w,
                                        (f16)p1.x,(f16)p1.y,(f16)p1.z,(f16)p1.w };
                            #pragma unroll
                            for (int nf = 0; nf < 4; ++nf) {
                                f16x8 w = *(const f16x8*)(wb + (ks * 4 + nf) * 1024);
                                acc[nf] = __builtin_amdgcn_mfma_f32_16x16x32_f16(w, v, acc[nf], 0, 0, 0);
                            }
                        }
                    } else {                                          // hh on h0(t-1), K=512
                        const char* p = (const char*)hprev + bb * 1024 + l4 * 16;
                        ldblob16(p, hv);
                        waitvm0();
                        const char* wb = lds + (size_t)64 * 1024 + lane * 16;
                        #pragma unroll
                        for (int ks = 0; ks < 16; ++ks) {
                            #pragma unroll
                            for (int nf = 0; nf < 4; ++nf) {
                                f16x8 w = *(const f16x8*)(wb + (ks * 4 + nf) * 1024);
                                acc[nf] = __builtin_amdgcn_mfma_f32_16x16x32_f16(w, hv[ks], acc[nf], 0, 0, 0);
                            }
                        }
                    }
                }
            } else {
                const int s = step;
                const f16* hsrc = (kh == 0) ? ((s & 1) ? h0b : h0a)   // ih: h0(s)
                                            : ((s & 1) ? h1a : h1b);  // hh: h1(s-1)
                const char* p = (const char*)hsrc + bb * 1024 + l4 * 16;
                ldblob16(p, hv);
                waitvm0();
                const char* wb = lds + (size_t)(kh * 64) * 1024 + lane * 16;
                #pragma unroll
                for (int ks = 0; ks < 16; ++ks) {
                    #pragma unroll
                    for (int nf = 0; nf < 4; ++nf) {
                        f16x8 w = *(const f16x8*)(wb + (ks * 4 + nf) * 1024);
                        acc[nf] = __builtin_amdgcn_mfma_f32_16x16x32_f16(w, hv[ks], acc[nf], 0, 0, 0);
                    }
                }
            }

            // ---- kh pair-reduce through LDS ----
            if (kh == 1) {
                #pragma unroll
                for (int nf = 0; nf < 4; ++nf)
                    *(f32x4*)(Rbuf + (((mfg * 4 + nf) * 64) + lane) * 16) = acc[nf];
            }
            __syncthreads();
            if (kh == 0) {
                #pragma unroll
                for (int nf = 0; nf < 4; ++nf)
                    acc[nf] += *(const f32x4*)(Rbuf + (((mfg * 4 + nf) * 64) + lane) * 16);

                const bool msk = step < lb;
                #pragma unroll
                for (int nf = 0; nf < 4; ++nf) {
                    float g0, g1, g2, g3;
                    if (layer == 0 && pre) {
                        g0 = (float)x0v[nf][0]; g1 = (float)x0v[nf][1];
                        g2 = (float)x0v[nf][2]; g3 = (float)x0v[nf][3];
                    } else {
                        g0 = bias4[nf].x; g1 = bias4[nf].y; g2 = bias4[nf].z; g3 = bias4[nf].w;
                    }
                    const float gi = acc[nf][0] + g0, gf = acc[nf][1] + g1;
                    const float gg = acc[nf][2] + g2, go = acc[nf][3] + g3;
                    const float cn = (1.f / (1.f + expf(-gf))) * c_s[nf]
                                   + (1.f / (1.f + expf(-gi))) * tanhf(gg);
                    const float hn = (1.f / (1.f + expf(-go))) * tanhf(cn);
                    if (msk) { c_s[nf] = cn; h_s[nf] = (f16)hn; }
                    // stage h into LDS: hstage[batch_local][unit_local] f16
                    *(f16*)(hstage + (mfg * 16 + l16) * 32 + (nf * 4 + l4) * 2) = h_s[nf];
                    if (layer == 1 && step == lb - 1)
                        h1f[(size_t)bb * 512 + cg * 16 + nf * 4 + l4] = hn;
                }
            }
            __syncthreads();
            // ---- coalesced 16B write-through h stores (threads 0..127) ----
            if (tid < 128) {
                f16* hw = (layer == 0) ? ((t & 1) ? h0b : h0a)        // h0(t)
                                       : ((step & 1) ? h1b : h1a);    // h1(s)
                const int bl = tid >> 1, half = tid & 1;
                f16x8 v = *(const f16x8*)(hstage + bl * 32 + half * 16);
                stwt16((char*)hw + (size_t)(bg * 64 + bl) * 1024 + cg * 32 + half * 16, v);
            }
        }

        // ---- direct-poll sub-grid barrier (64 blocks per bg) ----
        __syncthreads();                  // drains all stores (vmcnt 0 per wave)
        if (tid == 0)
            __hip_atomic_store(&slots[sidx * 4], t + 1, __ATOMIC_RELAXED, __HIP_MEMORY_SCOPE_AGENT);
        if (tid < 64) {                   // wave 0: lane i polls slot i
            while (__any(__hip_atomic_load(&slots[tid * 4], __ATOMIC_RELAXED,
                                           __HIP_MEMORY_SCOPE_AGENT) <= t))
                __builtin_amdgcn_s_sleep(1);
        }
        __syncthreads();
    }
}

// ---------------- final FC ----------------
__global__ __launch_bounds__(256) void k_fc(const float* __restrict__ h1f,
                                            const float* __restrict__ wfc,
                                            const float* __restrict__ bfc,
                                            float* __restrict__ out) {
    int b = blockIdx.x;
    float s0 = 0, s1 = 0, s2 = 0, s3 = 0;
    for (int h = threadIdx.x; h < 512; h += 256) {
        float v = h1f[(size_t)b * 512 + h];
        s0 += v * wfc[h];
        s1 += v * wfc[512 + h];
        s2 += v * wfc[1024 + h];
        s3 += v * wfc[1536 + h];
    }
    #pragma unroll
    for (int off = 32; off; off >>= 1) {
        s0 += __shfl_down(s0, off);
        s1 += __shfl_down(s1, off);
        s2 += __shfl_down(s2, off);
        s3 += __shfl_down(s3, off);
    }
    __shared__ float red[4][4];
    int wid = threadIdx.x >> 6;
    if ((threadIdx.x & 63) == 0) { red[wid][0] = s0; red[wid][1] = s1; red[wid][2] = s2; red[wid][3] = s3; }
    __syncthreads();
    if (threadIdx.x < 4) {
        float s = red[0][threadIdx.x] + red[1][threadIdx.x] + red[2][threadIdx.x] + red[3][threadIdx.x]
                + bfc[threadIdx.x];
        out[b * 4 + threadIdx.x] = s;
    }
}

extern "C" void kernel_launch(void* const* d_in, const int* in_sizes, int n_in,
                              void* d_out, int out_size, void* d_ws, size_t ws_size,
                              hipStream_t stream) {
    const float* x    = (const float*)d_in[0];
    const float* wih0 = (const float*)d_in[1];
    const float* whh0 = (const float*)d_in[2];
    const float* bih0 = (const float*)d_in[3];
    const float* bhh0 = (const float*)d_in[4];
    const float* wih1 = (const float*)d_in[5];
    const float* whh1 = (const float*)d_in[6];
    const float* bih1 = (const float*)d_in[7];
    const float* bhh1 = (const float*)d_in[8];
    const float* wfc  = (const float*)d_in[9];
    const float* bfc  = (const float*)d_in[10];

    if (ws_size < WS_BASE) return;
    const int pre = (ws_size >= WS_PRE) ? 1 : 0;

    char* ws = (char*)d_ws;
    int*   bar   = (int*)(ws + OFF_BAR);
    int*   len   = (int*)(ws + OFF_LEN);
    float* bias0 = (float*)(ws + OFF_BIAS0);
    float* bias1 = (float*)(ws + OFF_BIAS1);
    f16*   W0    = (f16*)(ws + OFF_W0);
    f16*   W1    = (f16*)(ws + OFF_W1);
    f16*   h0a   = (f16*)(ws + OFF_H0A);
    f16*   h0b   = (f16*)(ws + OFF_H0B);
    f16*   h1a   = (f16*)(ws + OFF_H1A);
    f16*   h1b   = (f16*)(ws + OFF_H1B);
    float* h1f   = (float*)(ws + OFF_H1F);
    f16*   X0p   = (f16*)(ws + OFF_X0);

    hipMemsetAsync(ws, 0, 4096, stream);                        // barrier slots + len
    hipMemsetAsync(ws + OFF_H0A, 0, WS_BASE - OFF_H0A, stream); // h state

    k_len<<<dim3(B_, 4), 512, 0, stream>>>(x, len);
    k_wcvt<<<2048, 256, 0, stream>>>(wih0, whh0, bih0, bhh0, W0, bias0);
    k_wcvt<<<2048, 256, 0, stream>>>(wih1, whh1, bih1, bhh1, W1, bias1);
    if (pre) k_xgemm<<<dim3(32, 128, 4), 256, 0, stream>>>(x, W0, bias0, X0p);

    hipFuncSetAttribute((const void*)k_persist, hipFuncAttributeMaxDynamicSharedMemorySize, 149504);
    const f16* X0c = X0p;
    void* kargs[] = {
        (void*)&x, (void*)&W0, (void*)&W1, (void*)&bias0, (void*)&bias1, (void*)&len,
        (void*)&h0a, (void*)&h0b, (void*)&h1a, (void*)&h1b, (void*)&h1f,
        (void*)&X0c, (void*)&pre, (void*)&bar
    };
    hipLaunchCooperativeKernel((const void*)k_persist, dim3(NBLK), dim3(512),
                               kargs, 149504, stream);

    k_fc<<<B_, 256, 0, stream>>>(h1f, wfc, bfc, (float*)d_out);
}

// Round 9
// 4014.606 us; speedup vs baseline: 4.8952x; 1.5452x over previous
//
#include <hip/hip_runtime.h>
#include <hip/hip_fp16.h>

typedef _Float16 f16;
typedef _Float16 f16x8 __attribute__((ext_vector_type(8)));
typedef _Float16 f16x4 __attribute__((ext_vector_type(4)));
typedef float f32x4 __attribute__((ext_vector_type(4)));

#define B_ 128
#define T_ 512
#define NBLK 256

// ---------------- workspace layout (bytes) ----------------
static constexpr size_t OFF_BAR   = 0;                         // 8 groups x 32 slots x 16B = 4KB
static constexpr size_t OFF_LEN   = 4096;                      // 128 int
static constexpr size_t OFF_BIAS0 = 8192;                      // 2048 f32
static constexpr size_t OFF_BIAS1 = 16384;                     // 2048 f32
static constexpr size_t OFF_W0    = 32768;                     // 2048x1024 f16, rows u*4+g, [w_ih|w_hh]
static constexpr size_t OFF_W1    = OFF_W0 + 4u*1024u*1024u;
static constexpr size_t OFF_H0    = OFF_W1 + 4u*1024u*1024u;   // 4 bufs x 128x512 f16
static constexpr size_t OFF_H1    = OFF_H0 + 4u*131072u;       // 2 bufs x 128x512 f16
static constexpr size_t OFF_H1F   = OFF_H1 + 2u*131072u;       // 128x512 f32
static constexpr size_t WS_BASE   = OFF_H1F + 262144;
static constexpr size_t OFF_X0    = WS_BASE;                   // f16 [T][B][2048]
static constexpr size_t X0_SZ     = (size_t)T_ * 128 * 2048 * 2;
static constexpr size_t WS_PRE    = OFF_X0 + X0_SZ;

// ---- batched mall-coherent load blobs (issue -> IMMEDIATE waitvm0; never defer) ----
__device__ __forceinline__ void ldblob16(const void* p, f16x8* v) {
    asm volatile(
        "global_load_dwordx4 %0, %16, off offset:0 sc0 sc1\n\t"
        "global_load_dwordx4 %1, %16, off offset:64 sc0 sc1\n\t"
        "global_load_dwordx4 %2, %16, off offset:128 sc0 sc1\n\t"
        "global_load_dwordx4 %3, %16, off offset:192 sc0 sc1\n\t"
        "global_load_dwordx4 %4, %16, off offset:256 sc0 sc1\n\t"
        "global_load_dwordx4 %5, %16, off offset:320 sc0 sc1\n\t"
        "global_load_dwordx4 %6, %16, off offset:384 sc0 sc1\n\t"
        "global_load_dwordx4 %7, %16, off offset:448 sc0 sc1\n\t"
        "global_load_dwordx4 %8, %16, off offset:512 sc0 sc1\n\t"
        "global_load_dwordx4 %9, %16, off offset:576 sc0 sc1\n\t"
        "global_load_dwordx4 %10, %16, off offset:640 sc0 sc1\n\t"
        "global_load_dwordx4 %11, %16, off offset:704 sc0 sc1\n\t"
        "global_load_dwordx4 %12, %16, off offset:768 sc0 sc1\n\t"
        "global_load_dwordx4 %13, %16, off offset:832 sc0 sc1\n\t"
        "global_load_dwordx4 %14, %16, off offset:896 sc0 sc1\n\t"
        "global_load_dwordx4 %15, %16, off offset:960 sc0 sc1"
        : "=&v"(v[0]), "=&v"(v[1]), "=&v"(v[2]), "=&v"(v[3]),
          "=&v"(v[4]), "=&v"(v[5]), "=&v"(v[6]), "=&v"(v[7]),
          "=&v"(v[8]), "=&v"(v[9]), "=&v"(v[10]), "=&v"(v[11]),
          "=&v"(v[12]), "=&v"(v[13]), "=&v"(v[14]), "=&v"(v[15])
        : "v"(p) : "memory");
}
__device__ __forceinline__ void ldblob8(const void* p, f16x8* v) {
    asm volatile(
        "global_load_dwordx4 %0, %8, off offset:0 sc0 sc1\n\t"
        "global_load_dwordx4 %1, %8, off offset:64 sc0 sc1\n\t"
        "global_load_dwordx4 %2, %8, off offset:128 sc0 sc1\n\t"
        "global_load_dwordx4 %3, %8, off offset:192 sc0 sc1\n\t"
        "global_load_dwordx4 %4, %8, off offset:256 sc0 sc1\n\t"
        "global_load_dwordx4 %5, %8, off offset:320 sc0 sc1\n\t"
        "global_load_dwordx4 %6, %8, off offset:384 sc0 sc1\n\t"
        "global_load_dwordx4 %7, %8, off offset:448 sc0 sc1"
        : "=&v"(v[0]), "=&v"(v[1]), "=&v"(v[2]), "=&v"(v[3]),
          "=&v"(v[4]), "=&v"(v[5]), "=&v"(v[6]), "=&v"(v[7])
        : "v"(p) : "memory");
}
__device__ __forceinline__ void waitvm0() {
    asm volatile("s_waitcnt vmcnt(0)" ::: "memory");
    __builtin_amdgcn_sched_barrier(0);
}
__device__ __forceinline__ void stwt16(void* p, f16x8 v) {
    asm volatile("global_store_dwordx4 %0, %1, off sc0 sc1" :: "v"(p), "v"(v) : "memory");
}

// ---------------- lengths ----------------
__global__ __launch_bounds__(512) void k_len(const float* __restrict__ x, int* __restrict__ len) {
    int b = blockIdx.x, q = blockIdx.y;
    int rl = threadIdx.x >> 2, part = threadIdx.x & 3;
    const float4* p = (const float4*)(x + ((size_t)b * T_ + q * 128 + rl) * 512 + part * 128);
    float s = 0.f;
    #pragma unroll
    for (int i = 0; i < 32; ++i) { float4 v = p[i]; s += v.x + v.y + v.z + v.w; }
    s += __shfl_xor(s, 1);
    s += __shfl_xor(s, 2);
    int cnt = __syncthreads_count(part == 0 && s != 0.0f);
    if (threadIdx.x == 0) atomicAdd(&len[b], cnt);
}

// ---------------- weight convert: rows u*4+gate, [w_ih|w_hh], f32->f16 ----------------
__global__ __launch_bounds__(256) void k_wcvt(const float* __restrict__ wih, const float* __restrict__ whh,
                                              const float* __restrict__ bih, const float* __restrict__ bhh,
                                              f16* __restrict__ W, float* __restrict__ bias) {
    int r = blockIdx.x;
    int h = r >> 2, g = r & 3;
    int src = g * 512 + h;
    const float* a = wih + (size_t)src * 512;
    const float* bsrc = whh + (size_t)src * 512;
    f16* dst = W + (size_t)r * 1024;
    #pragma unroll
    for (int j = 0; j < 2; ++j) {
        int k = threadIdx.x + j * 256;
        dst[k]       = (f16)a[k];
        dst[k + 512] = (f16)bsrc[k];
    }
    if (threadIdx.x == 0) bias[r] = bih[src] + bhh[src];
}

// ---------------- X0 precompute, x-stationary ----------------
// grid (b=128, tc=8), 256 thr. x tile (64t x 512) f16 frag-major in LDS (read once from HBM);
// W streamed per-cg (L2/L3-hot). Output repacked via LDS -> coalesced 128B NT stores.
__global__ __launch_bounds__(256) void k_xgemm(const float* __restrict__ x, const f16* __restrict__ W0,
                                               const float* __restrict__ bias0, f16* __restrict__ X0) {
    extern __shared__ char lds[];          // 64K xtile + 64K wtile + 8K outstage
    char* xt = lds;
    char* wt = lds + 65536;
    char* ot = lds + 131072;
    const int b = blockIdx.x, tc = blockIdx.y;
    const int tid = threadIdx.x;
    const int tf = tid >> 6, lane = tid & 63;
    const int l16 = lane & 15, l4 = lane >> 4;

    {   // stage x tile: B-operand frag-major. frag (tf,ks) at (tf*16+ks)*1024
        const int t = tid >> 2, q = tid & 3;
        const float* src = x + ((size_t)b * 512 + tc * 64 + t) * 512 + q * 128;
        #pragma unroll
        for (int j = 0; j < 16; ++j) {
            const float4 p0 = *(const float4*)(src + j * 8);
            const float4 p1 = *(const float4*)(src + j * 8 + 4);
            f16x8 v = { (f16)p0.x,(f16)p0.y,(f16)p0.z,(f16)p0.w,
                        (f16)p1.x,(f16)p1.y,(f16)p1.z,(f16)p1.w };
            const int k = q * 128 + j * 8;
            *(f16x8*)(xt + ((t >> 4) * 16 + (k >> 5)) * 1024
                         + ((t & 15) + ((k >> 3) & 3) * 16) * 16) = v;
        }
    }
    __syncthreads();

    for (int cg = 0; cg < 32; ++cg) {
        {   // stage W tile (ih half): A-operand frag-major. frag (ks,nf) at (ks*4+nf)*1024
            const int r = tid >> 2, q = tid & 3;
            const f16* src = W0 + (size_t)(cg * 64 + r) * 1024 + q * 128;
            #pragma unroll
            for (int j = 0; j < 16; ++j) {
                f16x8 w = *(const f16x8*)(src + j * 8);
                const int k = q * 128 + j * 8;
                *(f16x8*)(wt + ((k >> 5) * 4 + (r >> 4)) * 1024
                             + ((r & 15) + ((k >> 3) & 3) * 16) * 16) = w;
            }
        }
        __syncthreads();
        f32x4 acc[4] = {};
        #pragma unroll
        for (int ks = 0; ks < 16; ++ks) {
            f16x8 bx = *(const f16x8*)(xt + (tf * 16 + ks) * 1024 + lane * 16);
            #pragma unroll
            for (int nf = 0; nf < 4; ++nf) {
                f16x8 aw = *(const f16x8*)(wt + (ks * 4 + nf) * 1024 + lane * 16);
                acc[nf] = __builtin_amdgcn_mfma_f32_16x16x32_f16(aw, bx, acc[nf], 0, 0, 0);
            }
        }
        {   // bias + pack to outstage (swizzled)
            const int t = tf * 16 + l16;
            const int sw = (t & 7) << 4;
            #pragma unroll
            for (int nf = 0; nf < 4; ++nf) {
                const float4 b4 = *(const float4*)(bias0 + cg * 64 + nf * 16 + l4 * 4);
                f16x4 v = { (f16)(acc[nf][0] + b4.x), (f16)(acc[nf][1] + b4.y),
                            (f16)(acc[nf][2] + b4.z), (f16)(acc[nf][3] + b4.w) };
                const int byte = t * 128 + nf * 32 + l4 * 8;
                *(f16x4*)(ot + (byte ^ sw)) = v;
            }
        }
        __syncthreads();
        {   // coalesced NT store: 4 threads cover one t-row's 128B
            const int t = tid >> 2, ch = tid & 3;
            const int sw = (t & 7) << 4;
            const int byte = t * 128 + ch * 32;
            f16x8 v0 = *(const f16x8*)(ot + (byte ^ sw));
            f16x8 v1 = *(const f16x8*)(ot + ((byte + 16) ^ sw));
            f16* dst = X0 + ((size_t)(tc * 64 + t) * 128 + b) * 2048 + cg * 64 + ch * 16;
            __builtin_nontemporal_store(v0, (f16x8*)dst);
            __builtin_nontemporal_store(v1, (f16x8*)(dst + 8));
        }
        __syncthreads();
    }
}

// ---------------- persistent kernel ----------------
// 256 blocks x 512 thr (1/CU). Block = layer (bid>>7) x bg (bid>>5)&3 (32 batches) x cg (bid&31).
// Waves: kh (K-half/operand) x mfg (16-batch) x nfg (2 n-frags). Weights frag-major in LDS.
// Sync: per-(layer,bg) 32-slot epoch arrays. L0 polls own group (thr t) + L1 lap-guard (thr t-2);
// L1 polls L0 group + own group (thr t). h0 4-deep buffered, h1 2-deep. No fences.
// X0 epilogue operand: compiler-visible nontemporal loads (compiler inserts waitcnt; never
// hold an asm-load result across a deferred wait — that was round 8's bug).
__global__ __launch_bounds__(512, 2) void k_persist(
    const float* __restrict__ x,
    const f16* __restrict__ W0, const f16* __restrict__ W1,
    const float* __restrict__ bias0, const float* __restrict__ bias1,
    const int* __restrict__ len,
    f16* __restrict__ h0, f16* __restrict__ h1,
    float* __restrict__ h1f,
    const f16* __restrict__ X0, int pre, int* bar)
{
    extern __shared__ char lds[];          // 128K weights + 8K Rbuf + 1K hstage
    char* Rbuf   = lds + 131072;
    char* hstage = lds + 139264;
    const int tid = threadIdx.x;
    const int bid = blockIdx.x;
    const int layer = bid >> 7;
    const int bg = (bid >> 5) & 3;
    const int cg = bid & 31;
    const int wv = tid >> 6, lane = tid & 63;
    const int kh = wv & 1, mfg = (wv >> 1) & 1, nfg = wv >> 2;
    const int l16 = lane & 15, l4 = lane >> 4;

    {   // stage this block's 64 weight rows, frag-major
        const f16* Wsrc = (layer ? W1 : W0) + (size_t)(cg * 64) * 1024;
        #pragma unroll
        for (int j = 0; j < 16; ++j) {
            int cid = j * 512 + tid;
            int r = cid >> 7, kc = cid & 127;
            f16x8 w = *(const f16x8*)(Wsrc + (size_t)r * 1024 + kc * 8);
            int f = (kc >> 6) * 64 + ((kc >> 2) & 15) * 4 + (r >> 4);
            *(f16x8*)(lds + f * 1024 + ((kc & 3) * 16 + (r & 15)) * 16) = w;
        }
    }

    const int bb = bg * 32 + mfg * 16 + l16;       // this lane's batch
    const int lb = len[bb];
    float4 bias4[2];
    #pragma unroll
    for (int ni = 0; ni < 2; ++ni) {
        const int u = cg * 16 + (nfg * 2 + ni) * 4 + l4;
        if (layer) bias4[ni] = *(const float4*)(bias1 + u * 4);
        else if (!pre) bias4[ni] = *(const float4*)(bias0 + u * 4);
        else bias4[ni] = make_float4(0.f, 0.f, 0.f, 0.f);
    }
    float c_s[2] = {};
    f16 h_s[2] = {};

    __syncthreads();

    for (int t = 0; t <= T_; ++t) {
        // ---- poll (wave 0): lanes 0..31 -> L0[bg] slots, 32..63 -> L1[bg] slots ----
        if (tid < 64) {
            const int which = tid >> 5;
            const int thr = (layer == 0) ? (which ? t - 2 : t) : t;
            int* ap = bar + (which * 4 + bg) * 128 + (tid & 31) * 4;
            while (__any(__hip_atomic_load(ap, __ATOMIC_RELAXED, __HIP_MEMORY_SCOPE_AGENT) < thr))
                __builtin_amdgcn_s_sleep(1);
        }
        __syncthreads();

        const int step = layer ? (t - 1) : t;
        const bool active = (step >= 0) && (step < T_);
        if (active) {
            f32x4 acc[2] = {};
            f16x8 hv[16];
            f16x4 x0v[2];

            if (layer == 0) {
                const f16* hprev = h0 + (size_t)((t - 1) & 3) * 65536;
                if (pre) {
                    if (kh == 0) {       // X0 for epilogue: compiler-visible loads, issued early
                        #pragma unroll
                        for (int ni = 0; ni < 2; ++ni)
                            x0v[ni] = __builtin_nontemporal_load(
                                (const f16x4*)(X0 + ((size_t)t * 128 + bb) * 2048
                                               + (size_t)(cg * 16 + (nfg * 2 + ni) * 4 + l4) * 4));
                    }
                    const char* p = (const char*)hprev + bb * 1024 + kh * 512 + l4 * 16;
                    ldblob8(p, hv);
                    waitvm0();
                    const char* wb = lds + (size_t)(64 + kh * 32 + nfg * 2) * 1024 + lane * 16;
                    #pragma unroll
                    for (int ks = 0; ks < 8; ++ks) {
                        f16x8 w0 = *(const f16x8*)(wb + ks * 4096);
                        f16x8 w1 = *(const f16x8*)(wb + ks * 4096 + 1024);
                        acc[0] = __builtin_amdgcn_mfma_f32_16x16x32_f16(w0, hv[ks], acc[0], 0, 0, 0);
                        acc[1] = __builtin_amdgcn_mfma_f32_16x16x32_f16(w1, hv[ks], acc[1], 0, 0, 0);
                    }
                } else {
                    if (kh == 0) {                 // ih on x (f32->f16), K=512
                        const float* xp = x + ((size_t)bb * 512 + t) * 512 + l4 * 8;
                        const char* wb = lds + (size_t)(nfg * 2) * 1024 + lane * 16;
                        #pragma unroll
                        for (int ks = 0; ks < 16; ++ks) {
                            const float4 p0 = *(const float4*)(xp + ks * 32);
                            const float4 p1 = *(const float4*)(xp + ks * 32 + 4);
                            f16x8 v = { (f16)p0.x,(f16)p0.y,(f16)p0.z,(f16)p0.w,
                                        (f16)p1.x,(f16)p1.y,(f16)p1.z,(f16)p1.w };
                            f16x8 w0 = *(const f16x8*)(wb + ks * 4096);
                            f16x8 w1 = *(const f16x8*)(wb + ks * 4096 + 1024);
                            acc[0] = __builtin_amdgcn_mfma_f32_16x16x32_f16(w0, v, acc[0], 0, 0, 0);
                            acc[1] = __builtin_amdgcn_mfma_f32_16x16x32_f16(w1, v, acc[1], 0, 0, 0);
                        }
                    } else {                       // hh on h0(t-1), K=512
                        const char* p = (const char*)hprev + bb * 1024 + l4 * 16;
                        ldblob16(p, hv);
                        waitvm0();
                        const char* wb = lds + (size_t)(64 + nfg * 2) * 1024 + lane * 16;
                        #pragma unroll
                        for (int ks = 0; ks < 16; ++ks) {
                            f16x8 w0 = *(const f16x8*)(wb + ks * 4096);
                            f16x8 w1 = *(const f16x8*)(wb + ks * 4096 + 1024);
                            acc[0] = __builtin_amdgcn_mfma_f32_16x16x32_f16(w0, hv[ks], acc[0], 0, 0, 0);
                            acc[1] = __builtin_amdgcn_mfma_f32_16x16x32_f16(w1, hv[ks], acc[1], 0, 0, 0);
                        }
                    }
                }
            } else {
                const int s = step;
                const f16* src = (kh == 0) ? (h0 + (size_t)(s & 3) * 65536)        // ih: h0(s)
                                           : (h1 + (size_t)((s - 1) & 1) * 65536); // hh: h1(s-1)
                const char* p = (const char*)src + bb * 1024 + l4 * 16;
                ldblob16(p, hv);
                waitvm0();
                const char* wb = lds + (size_t)(kh * 64 + nfg * 2) * 1024 + lane * 16;
                #pragma unroll
                for (int ks = 0; ks < 16; ++ks) {
                    f16x8 w0 = *(const f16x8*)(wb + ks * 4096);
                    f16x8 w1 = *(const f16x8*)(wb + ks * 4096 + 1024);
                    acc[0] = __builtin_amdgcn_mfma_f32_16x16x32_f16(w0, hv[ks], acc[0], 0, 0, 0);
                    acc[1] = __builtin_amdgcn_mfma_f32_16x16x32_f16(w1, hv[ks], acc[1], 0, 0, 0);
                }
            }

            // ---- kh pair-reduce ----
            if (kh == 1) {
                #pragma unroll
                for (int ni = 0; ni < 2; ++ni)
                    *(f32x4*)(Rbuf + (((mfg * 2 + nfg) * 2 + ni) * 64 + lane) * 16) = acc[ni];
            }
            __syncthreads();
            if (kh == 0) {
                #pragma unroll
                for (int ni = 0; ni < 2; ++ni)
                    acc[ni] += *(const f32x4*)(Rbuf + (((mfg * 2 + nfg) * 2 + ni) * 64 + lane) * 16);

                const bool msk = step < lb;
                #pragma unroll
                for (int ni = 0; ni < 2; ++ni) {
                    float g0, g1, g2, g3;
                    if (layer == 0 && pre) {
                        g0 = (float)x0v[ni][0]; g1 = (float)x0v[ni][1];
                        g2 = (float)x0v[ni][2]; g3 = (float)x0v[ni][3];
                    } else {
                        g0 = bias4[ni].x; g1 = bias4[ni].y; g2 = bias4[ni].z; g3 = bias4[ni].w;
                    }
                    const float gi = acc[ni][0] + g0, gf = acc[ni][1] + g1;
                    const float gg = acc[ni][2] + g2, go = acc[ni][3] + g3;
                    const float cn = (1.f / (1.f + expf(-gf))) * c_s[ni]
                                   + (1.f / (1.f + expf(-gi))) * tanhf(gg);
                    const float hn = (1.f / (1.f + expf(-go))) * tanhf(cn);
                    if (msk) { c_s[ni] = cn; h_s[ni] = (f16)hn; }
                    *(f16*)(hstage + (mfg * 16 + l16) * 32 + ((nfg * 2 + ni) * 4 + l4) * 2) = h_s[ni];
                    if (layer == 1 && step == lb - 1)
                        h1f[(size_t)bb * 512 + cg * 16 + (nfg * 2 + ni) * 4 + l4] = hn;
                }
            }
            __syncthreads();
            if (tid < 64) {   // coalesced 16B write-through h stores
                f16* hw = (layer == 0) ? (h0 + (size_t)(t & 3) * 65536)
                                       : (h1 + (size_t)(step & 1) * 65536);
                const int bl = tid >> 1, half = tid & 1;
                f16x8 v = *(const f16x8*)(hstage + bl * 32 + half * 16);
                stwt16((char*)hw + (size_t)(bg * 32 + bl) * 1024 + cg * 32 + half * 16, v);
            }
        }

        __syncthreads();      // drain stores before publishing
        if (tid == 0)
            __hip_atomic_store(bar + (layer * 4 + bg) * 128 + cg * 4, t + 1,
                               __ATOMIC_RELAXED, __HIP_MEMORY_SCOPE_AGENT);
    }
}

// ---------------- final FC ----------------
__global__ __launch_bounds__(256) void k_fc(const float* __restrict__ h1f,
                                            const float* __restrict__ wfc,
                                            const float* __restrict__ bfc,
                                            float* __restrict__ out) {
    int b = blockIdx.x;
    float s0 = 0, s1 = 0, s2 = 0, s3 = 0;
    for (int h = threadIdx.x; h < 512; h += 256) {
        float v = h1f[(size_t)b * 512 + h];
        s0 += v * wfc[h];
        s1 += v * wfc[512 + h];
        s2 += v * wfc[1024 + h];
        s3 += v * wfc[1536 + h];
    }
    #pragma unroll
    for (int off = 32; off; off >>= 1) {
        s0 += __shfl_down(s0, off);
        s1 += __shfl_down(s1, off);
        s2 += __shfl_down(s2, off);
        s3 += __shfl_down(s3, off);
    }
    __shared__ float red[4][4];
    int wid = threadIdx.x >> 6;
    if ((threadIdx.x & 63) == 0) { red[wid][0] = s0; red[wid][1] = s1; red[wid][2] = s2; red[wid][3] = s3; }
    __syncthreads();
    if (threadIdx.x < 4) {
        float s = red[0][threadIdx.x] + red[1][threadIdx.x] + red[2][threadIdx.x] + red[3][threadIdx.x]
                + bfc[threadIdx.x];
        out[b * 4 + threadIdx.x] = s;
    }
}

extern "C" void kernel_launch(void* const* d_in, const int* in_sizes, int n_in,
                              void* d_out, int out_size, void* d_ws, size_t ws_size,
                              hipStream_t stream) {
    const float* x    = (const float*)d_in[0];
    const float* wih0 = (const float*)d_in[1];
    const float* whh0 = (const float*)d_in[2];
    const float* bih0 = (const float*)d_in[3];
    const float* bhh0 = (const float*)d_in[4];
    const float* wih1 = (const float*)d_in[5];
    const float* whh1 = (const float*)d_in[6];
    const float* bih1 = (const float*)d_in[7];
    const float* bhh1 = (const float*)d_in[8];
    const float* wfc  = (const float*)d_in[9];
    const float* bfc  = (const float*)d_in[10];

    if (ws_size < WS_BASE) return;
    const int pre = (ws_size >= WS_PRE) ? 1 : 0;

    char* ws = (char*)d_ws;
    int*   bar   = (int*)(ws + OFF_BAR);
    int*   len   = (int*)(ws + OFF_LEN);
    float* bias0 = (float*)(ws + OFF_BIAS0);
    float* bias1 = (float*)(ws + OFF_BIAS1);
    f16*   W0    = (f16*)(ws + OFF_W0);
    f16*   W1    = (f16*)(ws + OFF_W1);
    f16*   h0    = (f16*)(ws + OFF_H0);
    f16*   h1    = (f16*)(ws + OFF_H1);
    float* h1f   = (float*)(ws + OFF_H1F);
    f16*   X0p   = (f16*)(ws + OFF_X0);

    hipMemsetAsync(ws, 0, 8192, stream);                        // barrier slots + len
    hipMemsetAsync(ws + OFF_H0, 0, WS_BASE - OFF_H0, stream);   // h state + h1f

    k_len<<<dim3(B_, 4), 512, 0, stream>>>(x, len);
    k_wcvt<<<2048, 256, 0, stream>>>(wih0, whh0, bih0, bhh0, W0, bias0);
    k_wcvt<<<2048, 256, 0, stream>>>(wih1, whh1, bih1, bhh1, W1, bias1);
    if (pre) {
        hipFuncSetAttribute((const void*)k_xgemm, hipFuncAttributeMaxDynamicSharedMemorySize, 139264);
        k_xgemm<<<dim3(128, 8), 256, 139264, stream>>>(x, W0, bias0, X0p);
    }

    hipFuncSetAttribute((const void*)k_persist, hipFuncAttributeMaxDynamicSharedMemorySize, 140288);
    const f16* X0c = X0p;
    void* kargs[] = {
        (void*)&x, (void*)&W0, (void*)&W1, (void*)&bias0, (void*)&bias1, (void*)&len,
        (void*)&h0, (void*)&h1, (void*)&h1f,
        (void*)&X0c, (void*)&pre, (void*)&bar
    };
    hipLaunchCooperativeKernel((const void*)k_persist, dim3(NBLK), dim3(512),
                               kargs, 140288, stream);

    k_fc<<<B_, 256, 0, stream>>>(h1f, wfc, bfc, (float*)d_out);
}